// Round 14
// baseline (5309.107 us; speedup 1.0000x reference)
//
#include <hip/hip_runtime.h>
#include <math.h>

#define B_ 4
#define G_ 16906
#define D_ 256
#define H_ 8
#define DH_ 32
#define M_ 110
#define L_ 6
#define FF_ 1024
#define NSEQ (G_ + 1)          // 16907
#define NR (B_ * NSEQ)         // 67628
#define NRP_ 67712             // 529*128, row-padded for 128-tiles
#define NYT_ 529               // row tiles
#define BH_ 32                 // B_*H_
#define QS_ 768                // fused qkv row stride (q:0, k:256, v:512)

static constexpr float SCALE_  = 0.42044820762685725f;   // 32^-0.25
static constexpr float MSCALE_ = 0.09534625892455922f;   // 110^-0.5
static constexpr float FEPS_   = 1e-4f;

// ---- static workspace (module-load-time allocation; R1 proved d_ws too small) ----
#define SZP_ ((size_t)NRP_ * D_)                 // fp32 x buffer
#define WS_FLOATS 92000000                       // ~368 MB
__device__ float g_ws[WS_FLOATS];

typedef __attribute__((ext_vector_type(8))) short bh8;   // 8 bf16 (4 VGPR)
typedef __attribute__((ext_vector_type(4))) float f4;    // MFMA acc

// ---- helpers ----
__device__ __forceinline__ unsigned f2u(float f){
    unsigned u = __float_as_uint(f);
    return (u & 0x80000000u) ? ~u : (u | 0x80000000u);
}
__device__ __forceinline__ float u2f(unsigned u){
    return (u & 0x80000000u) ? __uint_as_float(u & 0x7fffffffu) : __uint_as_float(~u);
}
__device__ __forceinline__ unsigned short f2b(float f){   // fp32 -> bf16 RNE
    unsigned u = __float_as_uint(f);
    return (unsigned short)((u + 0x7fffu + ((u >> 16) & 1u)) >> 16);
}
__device__ __forceinline__ float bf2f(unsigned short u){
    return __uint_as_float(((unsigned)u) << 16);
}

// =============== preprocess ===============
__global__ void k_pre_init(unsigned* __restrict__ maxkey){
    if (threadIdx.x == 0) *maxkey = 0x007fffffu;  // f2u(-inf)
}

__global__ void k_rowsum(const float* __restrict__ expr, float* __restrict__ ssum){
    int b = blockIdx.x, t = threadIdx.x;
    float s = 0.f;
    for (int g = t; g < G_; g += 256) s += fabsf(expr[(size_t)b * G_ + g]);
    __shared__ float red[256];
    red[t] = s; __syncthreads();
    for (int off = 128; off > 0; off >>= 1){ if (t < off) red[t] += red[t + off]; __syncthreads(); }
    if (t == 0) ssum[b] = red[0];
}

__global__ void k_compute_e(const float* __restrict__ expr, const float* __restrict__ ssum,
                            float* __restrict__ ebuf, unsigned* __restrict__ maxkey){
    int t = threadIdx.x;
    int idx = blockIdx.x * 256 + t;
    float e = -INFINITY;
    if (idx < B_ * G_){
        int b = idx / G_;
        float denom = fmaxf(ssum[b], 1e-12f);
        e = log1pf(expr[idx] / denom * 1e4f);
        ebuf[idx] = e;
    }
    __shared__ float red[256];
    red[t] = e; __syncthreads();
    for (int off = 128; off > 0; off >>= 1){ if (t < off) red[t] = fmaxf(red[t], red[t + off]); __syncthreads(); }
    if (t == 0) atomicMax(maxkey, f2u(red[0]));
}

__global__ void k_embed(const float* __restrict__ ebuf, const unsigned* __restrict__ maxkey,
                        const float* __restrict__ tokemb, const float* __restrict__ cls,
                        float* __restrict__ x){
    int row = blockIdx.x, t = threadIdx.x;
    if (row >= NR){ x[(size_t)row * D_ + t] = 0.f; return; }   // pad rows -> 0
    int b = row / NSEQ, i = row % NSEQ;
    float v;
    if (i == 0){
        v = cls[t];
    } else {
        float e = ebuf[(size_t)b * G_ + (i - 1)];
        float mx = u2f(*maxkey);
        float step = mx / 7.0f;                 // linspace(0,mx,8)[:7] = step*j
        int cnt = 0;
        #pragma unroll
        for (int j = 0; j < 7; ++j){
            float bin = step * (float)j;
            cnt += (bin < e) ? 1 : 0;           // searchsorted side='left'
        }
        if (cnt > 6) cnt = 6;
        v = tokemb[cnt * D_ + t];
    }
    x[(size_t)row * D_ + t] = v;
}

// =============== layernorm: fp32 in, bf16 out ===============
__global__ void k_ln(const float* __restrict__ X, unsigned short* __restrict__ Y,
                     const float* __restrict__ g, const float* __restrict__ b){
    int row = blockIdx.x, t = threadIdx.x;
    float v = X[(size_t)row * D_ + t];
    __shared__ float red[256];
    red[t] = v; __syncthreads();
    for (int off = 128; off > 0; off >>= 1){ if (t < off) red[t] += red[t + off]; __syncthreads(); }
    float mu = red[0] * (1.0f / 256.0f);
    __syncthreads();
    float d = v - mu;
    red[t] = d * d; __syncthreads();
    for (int off = 128; off > 0; off >>= 1){ if (t < off) red[t] += red[t + off]; __syncthreads(); }
    float var = red[0] * (1.0f / 256.0f);
    Y[(size_t)row * D_ + t] = f2b(d * rsqrtf(var + 1e-5f) * g[t] + b[t]);
}

// =============== weight transpose + bf16 convert: Wout[n][k] = Win[k][n] ===============
__global__ void k_wconv(const float* __restrict__ Win, unsigned short* __restrict__ Wout,
                        int K, int N, int lstride){
    __shared__ float tile[32][33];
    int l = blockIdx.z;
    const float* W = Win + (size_t)l * K * N;
    unsigned short* O = Wout + (size_t)l * lstride;
    int n0 = blockIdx.x * 32, k0 = blockIdx.y * 32;
    int tx = threadIdx.x, ty = threadIdx.y;
    #pragma unroll
    for (int j = 0; j < 4; ++j)
        tile[ty + j * 8][tx] = W[(size_t)(k0 + ty + j * 8) * N + n0 + tx];
    __syncthreads();
    #pragma unroll
    for (int j = 0; j < 4; ++j){
        int n = ty + j * 8;
        O[(size_t)(n0 + n) * K + k0 + tx] = f2b(tile[tx][n]);
    }
}

__global__ void k_packbias(const float* __restrict__ bq, const float* __restrict__ bk,
                           const float* __restrict__ bv, float* __restrict__ o){
    int l = blockIdx.x, t = threadIdx.x;
    o[l * QS_ + t]        = bq[l * D_ + t];
    o[l * QS_ + 256 + t]  = bk[l * D_ + t];
    o[l * QS_ + 512 + t]  = bv[l * D_ + t];
}

// =============== bf16 MFMA GEMM: C = op(A @ Wt^T + bias) ===============
// MODE 0: Cf = A@W + bias (fp32)        MODE 1: Cf += A@W + bias (fp32 residual)
// MODE 2: Cb = bf16(gelu(A@W + bias))   MODE 3: Cb = bf16(A@W + bias)
// R12 XCD swizzle + R11 pipelined K-loop + R8 LDS bf16 epilogue.
// (R13 post-mortem: FFN fusion regressed — per-XCD L2 thrash on 8x A re-reads;
//  split FF1/FF2 retained.)
#define GP 40
#define EPIT 136
#define BUFSZ (2 * 128 * GP)   // one A+B pair (shorts)
template <int MODE>
__launch_bounds__(256)
__global__ void gemm_bf16(const unsigned short* __restrict__ A,
                          const unsigned short* __restrict__ Wt,
                          const float* __restrict__ bias,
                          float* __restrict__ Cf, unsigned short* __restrict__ Cb,
                          int K, int N, int NY){
    int NX = N >> 7;
    int lid = blockIdx.x;
    int xcd = lid & 7, slot = lid >> 3;
    int colt = slot % NX;
    int rowt = (slot / NX) * 8 + xcd;
    if (rowt >= NY) return;
    int rowBase = rowt * 128, colBase = colt * 128;

    __shared__ __align__(16) unsigned short smem[2 * BUFSZ];
    int tid = threadIdx.x;
    int lane = tid & 63, wave = tid >> 6;
    int wrow = (wave >> 1) * 64, wcol = (wave & 1) * 64;
    int srow = tid >> 2, sslot = tid & 3;
    int m = lane & 15, kg = lane >> 4;
    int sOff = srow * GP + sslot * 8;

    f4 acc[4][4];
    #pragma unroll
    for (int i = 0; i < 4; ++i)
        #pragma unroll
        for (int j = 0; j < 4; ++j) acc[i][j] = (f4){0.f, 0.f, 0.f, 0.f};

    const unsigned short* Ag = A + (size_t)(rowBase + srow) * K + sslot * 8;
    const unsigned short* Bg = Wt + (size_t)(colBase + srow) * K + sslot * 8;

    {
        uint4 a0 = *(const uint4*)(Ag);
        uint4 a1 = *(const uint4*)(Ag + (size_t)64 * K);
        uint4 b0 = *(const uint4*)(Bg);
        uint4 b1 = *(const uint4*)(Bg + (size_t)64 * K);
        *(uint4*)&smem[sOff] = a0;
        *(uint4*)&smem[64 * GP + sOff] = a1;
        *(uint4*)&smem[128 * GP + sOff] = b0;
        *(uint4*)&smem[128 * GP + 64 * GP + sOff] = b1;
    }
    const int NIT = K >> 5;
    for (int it = 0; it < NIT; ++it){
        __syncthreads();
        int cur = (it & 1) * BUFSZ;
        uint4 na0, na1, nb0, nb1;
        bool more = (it + 1 < NIT);
        if (more){
            int k0 = (it + 1) << 5;
            na0 = *(const uint4*)(Ag + k0);
            na1 = *(const uint4*)(Ag + (size_t)64 * K + k0);
            nb0 = *(const uint4*)(Bg + k0);
            nb1 = *(const uint4*)(Bg + (size_t)64 * K + k0);
        }
        bh8 af[4], bf[4];
        #pragma unroll
        for (int mi = 0; mi < 4; ++mi)
            af[mi] = *(const bh8*)&smem[cur + (wrow + mi * 16 + m) * GP + kg * 8];
        #pragma unroll
        for (int ni = 0; ni < 4; ++ni)
            bf[ni] = *(const bh8*)&smem[cur + 128 * GP + (wcol + ni * 16 + m) * GP + kg * 8];
        #pragma unroll
        for (int mi = 0; mi < 4; ++mi)
            #pragma unroll
            for (int ni = 0; ni < 4; ++ni)
                acc[mi][ni] = __builtin_amdgcn_mfma_f32_16x16x32_bf16(af[mi], bf[ni], acc[mi][ni], 0, 0, 0);
        if (more){
            int nxt = ((it + 1) & 1) * BUFSZ;
            *(uint4*)&smem[nxt + sOff] = na0;
            *(uint4*)&smem[nxt + 64 * GP + sOff] = na1;
            *(uint4*)&smem[nxt + 128 * GP + sOff] = nb0;
            *(uint4*)&smem[nxt + 128 * GP + 64 * GP + sOff] = nb1;
        }
    }
    __syncthreads();
    int q4 = lane >> 4;
    if (MODE == 0 || MODE == 1){
        #pragma unroll
        for (int ni = 0; ni < 4; ++ni){
            int col = colBase + wcol + ni * 16 + m;
            float bv = bias[col];
            #pragma unroll
            for (int mi = 0; mi < 4; ++mi){
                int r0 = rowBase + wrow + mi * 16 + q4 * 4;
                #pragma unroll
                for (int rg = 0; rg < 4; ++rg){
                    int row = r0 + rg;
                    float v = acc[mi][ni][rg] + bv;
                    if (MODE == 1) v += Cf[(size_t)row * N + col];
                    Cf[(size_t)row * N + col] = v;
                }
            }
        }
    } else {
        #pragma unroll
        for (int half = 0; half < 2; ++half){
            if ((wrow >> 6) == half){
                #pragma unroll
                for (int ni = 0; ni < 4; ++ni){
                    int coll = wcol + ni * 16 + m;
                    float bv = bias[colBase + coll];
                    #pragma unroll
                    for (int mi = 0; mi < 4; ++mi){
                        int rl0 = (wrow & 63) + mi * 16 + q4 * 4;
                        #pragma unroll
                        for (int rg = 0; rg < 4; ++rg){
                            float v = acc[mi][ni][rg] + bv;
                            if (MODE == 2) v = 0.5f * v * (1.0f + erff(v * 0.70710678118654752f));
                            smem[(rl0 + rg) * EPIT + coll] = f2b(v);
                        }
                    }
                }
            }
            __syncthreads();
            #pragma unroll
            for (int p = 0; p < 4; ++p){
                int idx = p * 256 + tid;
                int r = idx >> 4, ch = idx & 15;
                int grow = rowBase + half * 64 + r;
                uint4 val = *(const uint4*)&smem[r * EPIT + ch * 8];
                *(uint4*)&Cb[(size_t)grow * N + colBase + ch * 8] = val;
            }
            __syncthreads();
        }
    }
}

// =============== attention state init ===============
__global__ void k_layer_init(float* __restrict__ kfsum, float* __restrict__ ctx,
                             unsigned* __restrict__ stab){
    int t = blockIdx.x * 256 + threadIdx.x;
    int nt = gridDim.x * 256;
    if (t == 0) *stab = 0x007fffffu;  // f2u(-inf)
    for (int i = t; i < BH_ * M_; i += nt) kfsum[i] = 0.f;
    for (int i = t; i < BH_ * M_ * DH_; i += nt) ctx[i] = 0.f;
}

// =============== k_kmax: global max of dd (K-side) via MFMA ===============
__launch_bounds__(256)
__global__ void k_kmax(const unsigned short* __restrict__ qkv, const float* __restrict__ proj,
                       unsigned* __restrict__ stab){
    __shared__ __align__(16) unsigned short pjT[112 * 40];
    __shared__ __align__(16) unsigned short kl[32 * 40];
    __shared__ float red[256];
    int t = threadIdx.x, lane = t & 63, wave = t >> 6;
    int m16 = lane & 15, quad = lane >> 4;
    int bh = blockIdx.y, b = bh >> 3, hh = bh & 7;
    for (int e = t; e < 112 * 32; e += 256){
        int mm = e >> 5, d = e & 31;
        pjT[mm * 40 + d] = f2b((mm < M_) ? SCALE_ * proj[mm * DH_ + d] : 0.f);
    }
    int i0 = blockIdx.x * 256, i1 = min(i0 + 256, NSEQ);
    float mx = -INFINITY;
    __syncthreads();
    for (int t0 = i0; t0 < i1; t0 += 32){
        int rows = min(32, i1 - t0);
        for (int e = t; e < 32 * 32; e += 256){
            int i = e >> 5, d = e & 31;
            unsigned short v = 0;
            if (i < rows) v = qkv[((size_t)(b * NSEQ + t0 + i)) * QS_ + 256 + hh * DH_ + d];
            kl[i * 40 + d] = v;
        }
        __syncthreads();
        #pragma unroll
        for (int nn = 0; nn < 2; ++nn){
            int nt = wave + nn * 4;
            if (nt >= 7) continue;
            bh8 bfrag = *(const bh8*)&pjT[(nt * 16 + m16) * 40 + quad * 8];
            int f = nt * 16 + m16;
            #pragma unroll
            for (int mt = 0; mt < 2; ++mt){
                bh8 afrag = *(const bh8*)&kl[(mt * 16 + m16) * 40 + quad * 8];
                f4 dd = (f4){0.f,0.f,0.f,0.f};
                dd = __builtin_amdgcn_mfma_f32_16x16x32_bf16(afrag, bfrag, dd, 0, 0, 0);
                #pragma unroll
                for (int rg = 0; rg < 4; ++rg){
                    int r = mt * 16 + quad * 4 + rg;
                    if (f < M_ && r < rows) mx = fmaxf(mx, dd[rg]);
                }
            }
        }
        __syncthreads();
    }
    red[t] = mx; __syncthreads();
    for (int off = 128; off > 0; off >>= 1){ if (t < off) red[t] = fmaxf(red[t], red[t + off]); __syncthreads(); }
    if (t == 0) atomicMax(stab, f2u(red[0]));
}

// =============== k_kv: kf via dd-MFMA, ctx += kf^T @ V via MFMA ===============
// R14: diag computed inline from staged kl (k_diag pass eliminated)
__launch_bounds__(256)
__global__ void k_kv(const unsigned short* __restrict__ qkv,
                     const float* __restrict__ proj,
                     const unsigned* __restrict__ stabkey,
                     float* __restrict__ kfsum, float* __restrict__ ctx){
    __shared__ __align__(16) unsigned short pjT[112 * 40];
    __shared__ __align__(16) unsigned short kl[32 * 40];
    __shared__ __align__(16) unsigned short vT[32 * 40];
    __shared__ __align__(16) unsigned short kfT[112 * 40];
    __shared__ float diagl[32];
    int t = threadIdx.x, lane = t & 63, wave = t >> 6;
    int m16 = lane & 15, quad = lane >> 4;
    int bh = blockIdx.y, b = bh >> 3, hh = bh & 7;
    for (int e = t; e < 112 * 32; e += 256){
        int mm = e >> 5, d = e & 31;
        pjT[mm * 40 + d] = f2b((mm < M_) ? SCALE_ * proj[mm * DH_ + d] : 0.f);
    }
    float stab = u2f(*stabkey);
    f4 acc[2][2];
    #pragma unroll
    for (int i = 0; i < 2; ++i)
        #pragma unroll
        for (int j = 0; j < 2; ++j) acc[i][j] = (f4){0.f,0.f,0.f,0.f};
    float ksum = 0.f;
    int i0 = blockIdx.x * 256, i1 = min(i0 + 256, NSEQ);
    __syncthreads();
    for (int t0 = i0; t0 < i1; t0 += 32){
        int rows = min(32, i1 - t0);
        for (int e = t; e < 32 * 32; e += 256){
            int i = e >> 5, d = e & 31;
            unsigned short kvv = 0, vvv = 0;
            if (i < rows){
                size_t base = ((size_t)(b * NSEQ + t0 + i)) * QS_ + hh * DH_ + d;
                kvv = qkv[base + 256]; vvv = qkv[base + 512];
            }
            kl[i * 40 + d] = kvv;
            vT[d * 40 + i] = vvv;
        }
        __syncthreads();
        // inline diag: 8 threads/row, 4 squares each + xor-shuffle (R14)
        {
            int r = t >> 3, part = t & 7;
            float s = 0.f;
            #pragma unroll
            for (int d0 = 0; d0 < 4; ++d0){
                float kv = bf2f(kl[r * 40 + part * 4 + d0]);
                s += kv * kv;
            }
            s += __shfl_xor(s, 1); s += __shfl_xor(s, 2); s += __shfl_xor(s, 4);
            if (part == 0) diagl[r] = 0.5f * SCALE_ * SCALE_ * s;
        }
        __syncthreads();
        #pragma unroll
        for (int nn = 0; nn < 2; ++nn){
            int nt = wave + nn * 4;
            if (nt >= 7) continue;
            bh8 bfrag = *(const bh8*)&pjT[(nt * 16 + m16) * 40 + quad * 8];
            int f = nt * 16 + m16;
            #pragma unroll
            for (int mt = 0; mt < 2; ++mt){
                bh8 afrag = *(const bh8*)&kl[(mt * 16 + m16) * 40 + quad * 8];
                f4 dd = (f4){0.f,0.f,0.f,0.f};
                dd = __builtin_amdgcn_mfma_f32_16x16x32_bf16(afrag, bfrag, dd, 0, 0, 0);
                #pragma unroll
                for (int rg = 0; rg < 4; ++rg){
                    int r = mt * 16 + quad * 4 + rg;
                    float kf = 0.f;
                    if (r < rows) kf = MSCALE_ * (__expf(dd[rg] - diagl[r] - stab) + FEPS_);
                    kfT[f * 40 + r] = f2b(kf);
                }
            }
        }
        __syncthreads();
        #pragma unroll
        for (int mm = 0; mm < 2; ++mm){
            int mt = wave + mm * 4;
            if (mt >= 7) continue;
            bh8 afrag = *(const bh8*)&kfT[(mt * 16 + m16) * 40 + quad * 8];
            #pragma unroll
            for (int nt2 = 0; nt2 < 2; ++nt2){
                bh8 bfrag = *(const bh8*)&vT[(nt2 * 16 + m16) * 40 + quad * 8];
                acc[mm][nt2] = __builtin_amdgcn_mfma_f32_16x16x32_bf16(afrag, bfrag, acc[mm][nt2], 0, 0, 0);
            }
        }
        if (t < M_){
            for (int i = 0; i < rows; ++i) ksum += bf2f(kfT[t * 40 + i]);
        }
        __syncthreads();
    }
    float* ctx_bh = ctx + (size_t)bh * M_ * DH_;
    #pragma unroll
    for (int mm = 0; mm < 2; ++mm){
        int mt = wave + mm * 4;
        if (mt >= 7) continue;
        #pragma unroll
        for (int nt2 = 0; nt2 < 2; ++nt2){
            #pragma unroll
            for (int rg = 0; rg < 4; ++rg){
                int f = mt * 16 + quad * 4 + rg;
                int dh = nt2 * 16 + m16;
                if (f < M_) atomicAdd(&ctx_bh[f * DH_ + dh], acc[mm][nt2][rg]);
            }
        }
    }
    if (t < M_) atomicAdd(&kfsum[bh * M_ + t], ksum);
}

// =============== k_qattn: qf via dd-MFMA (rowmax), o = qf @ ctx via MFMA ===============
// R14: diagq computed inline from staged ql (uses existing rmax barrier)
#define CXP 136
__launch_bounds__(256)
__global__ void k_qattn(const unsigned short* __restrict__ qkv, const float* __restrict__ proj,
                        const float* __restrict__ kfsumg,
                        const float* __restrict__ ctxg, unsigned short* __restrict__ Ob){
    __shared__ __align__(16) unsigned short pjT[112 * 40];
    __shared__ __align__(16) unsigned short ql[32 * 40];
    __shared__ __align__(16) unsigned short qfl[32 * CXP];
    __shared__ __align__(16) unsigned short cxT[32 * CXP];
    __shared__ float kfs[112];
    __shared__ float diagl[32];
    __shared__ float rmax[4][32];
    __shared__ float denl[32];
    int t = threadIdx.x, lane = t & 63, wave = t >> 6;
    int m16 = lane & 15, quad = lane >> 4;
    int bh = blockIdx.y, b = bh >> 3, hh = bh & 7;
    const float* ctx_bh = ctxg + (size_t)bh * M_ * DH_;
    for (int e = t; e < 112 * 32; e += 256){
        int mm = e >> 5, d = e & 31;
        pjT[mm * 40 + d] = f2b((mm < M_) ? SCALE_ * proj[mm * DH_ + d] : 0.f);
    }
    for (int e = t; e < 32 * 128; e += 256){
        int dh = e >> 7, f = e & 127;
        cxT[dh * CXP + f] = f2b((f < M_) ? ctx_bh[f * DH_ + dh] : 0.f);
    }
    for (int e = t; e < 32 * CXP; e += 256) qfl[e] = 0;
    if (t < M_) kfs[t] = kfsumg[bh * M_ + t];
    int i0 = blockIdx.x * 256, i1 = min(i0 + 256, NSEQ);
    __syncthreads();
    for (int t0 = i0; t0 < i1; t0 += 32){
        int rows = min(32, i1 - t0);
        for (int e = t; e < 32 * 32; e += 256){
            int i = e >> 5, d = e & 31;
            unsigned short v = 0;
            if (i < rows) v = qkv[((size_t)(b * NSEQ + t0 + i)) * QS_ + hh * DH_ + d];
            ql[i * 40 + d] = v;
        }
        __syncthreads();
        // inline diagq (visible after the rmax barrier below)
        {
            int r = t >> 3, part = t & 7;
            float s = 0.f;
            #pragma unroll
            for (int d0 = 0; d0 < 4; ++d0){
                float qv = bf2f(ql[r * 40 + part * 4 + d0]);
                s += qv * qv;
            }
            s += __shfl_xor(s, 1); s += __shfl_xor(s, 2); s += __shfl_xor(s, 4);
            if (part == 0) diagl[r] = 0.5f * SCALE_ * SCALE_ * s;
        }
        f4 ddv[2][2];
        float pm[2][4];
        #pragma unroll
        for (int mt = 0; mt < 2; ++mt)
            #pragma unroll
            for (int rg = 0; rg < 4; ++rg) pm[mt][rg] = -INFINITY;
        #pragma unroll
        for (int nn = 0; nn < 2; ++nn){
            int nt = wave + nn * 4;
            if (nt >= 7) continue;
            bh8 bfrag = *(const bh8*)&pjT[(nt * 16 + m16) * 40 + quad * 8];
            int f = nt * 16 + m16;
            #pragma unroll
            for (int mt = 0; mt < 2; ++mt){
                bh8 afrag = *(const bh8*)&ql[(mt * 16 + m16) * 40 + quad * 8];
                f4 dd = (f4){0.f,0.f,0.f,0.f};
                dd = __builtin_amdgcn_mfma_f32_16x16x32_bf16(afrag, bfrag, dd, 0, 0, 0);
                ddv[nn][mt] = dd;
                if (f < M_){
                    #pragma unroll
                    for (int rg = 0; rg < 4; ++rg) pm[mt][rg] = fmaxf(pm[mt][rg], dd[rg]);
                }
            }
        }
        #pragma unroll
        for (int mt = 0; mt < 2; ++mt)
            #pragma unroll
            for (int rg = 0; rg < 4; ++rg){
                float v = pm[mt][rg];
                v = fmaxf(v, __shfl_xor(v, 1));
                v = fmaxf(v, __shfl_xor(v, 2));
                v = fmaxf(v, __shfl_xor(v, 4));
                v = fmaxf(v, __shfl_xor(v, 8));
                if (m16 == 0) rmax[wave][mt * 16 + quad * 4 + rg] = v;
            }
        __syncthreads();
        #pragma unroll
        for (int nn = 0; nn < 2; ++nn){
            int nt = wave + nn * 4;
            if (nt >= 7) continue;
            int f = nt * 16 + m16;
            #pragma unroll
            for (int mt = 0; mt < 2; ++mt){
                #pragma unroll
                for (int rg = 0; rg < 4; ++rg){
                    int r = mt * 16 + quad * 4 + rg;
                    float mx = fmaxf(fmaxf(rmax[0][r], rmax[1][r]), fmaxf(rmax[2][r], rmax[3][r]));
                    float qf = MSCALE_ * (__expf(ddv[nn][mt][rg] - diagl[r] - mx) + FEPS_);
                    qfl[r * CXP + f] = f2b(qf);
                }
            }
        }
        __syncthreads();
        {
            int r = t >> 3, part = t & 7;
            float s = 0.f;
            for (int f = part; f < M_; f += 8) s += bf2f(qfl[r * CXP + f]) * kfs[f];
            s += __shfl_xor(s, 4); s += __shfl_xor(s, 2); s += __shfl_xor(s, 1);
            if (part == 0) denl[r] = s;
        }
        __syncthreads();
        {
            int mt = wave >> 1, nt = wave & 1;
            f4 oacc = (f4){0.f,0.f,0.f,0.f};
            #pragma unroll
            for (int kk = 0; kk < 4; ++kk){
                bh8 afrag = *(const bh8*)&qfl[(mt * 16 + m16) * CXP + kk * 32 + quad * 8];
                bh8 bfrag = *(const bh8*)&cxT[(nt * 16 + m16) * CXP + kk * 32 + quad * 8];
                oacc = __builtin_amdgcn_mfma_f32_16x16x32_bf16(afrag, bfrag, oacc, 0, 0, 0);
            }
            #pragma unroll
            for (int rg = 0; rg < 4; ++rg){
                int r = mt * 16 + quad * 4 + rg;
                if (r < rows){
                    int grow = b * NSEQ + t0 + r;
                    float o = oacc[rg] / denl[r];
                    Ob[(size_t)grow * D_ + hh * DH_ + nt * 16 + m16] = f2b(o);
                }
            }
        }
        __syncthreads();
    }
}

// =============== final projection: out[b] = x[b,0] @ pw + pb (fp32) ===============
__global__ void k_final(const float* __restrict__ x, const float* __restrict__ pw,
                        const float* __restrict__ pb, float* __restrict__ out){
    int b = blockIdx.x, c = threadIdx.x;
    const float* xr = x + (size_t)b * NSEQ * D_;
    float s = pb[c];
    for (int k = 0; k < D_; ++k) s += xr[k] * pw[k * D_ + c];
    out[b * D_ + c] = s;
}

// =============== host launcher ===============
extern "C" void kernel_launch(void* const* d_in, const int* in_sizes, int n_in,
                              void* d_out, int out_size, void* d_ws, size_t ws_size,
                              hipStream_t stream){
    const float* expr   = (const float*)d_in[0];
    const float* tokemb = (const float*)d_in[1];
    const float* cls    = (const float*)d_in[2];
    const float* ln1g   = (const float*)d_in[3];
    const float* ln1b   = (const float*)d_in[4];
    const float* wq     = (const float*)d_in[5];
    const float* bq     = (const float*)d_in[6];
    const float* wk     = (const float*)d_in[7];
    const float* bk     = (const float*)d_in[8];
    const float* wv     = (const float*)d_in[9];
    const float* bv     = (const float*)d_in[10];
    const float* wo     = (const float*)d_in[11];
    const float* bo     = (const float*)d_in[12];
    const float* ln2g   = (const float*)d_in[13];
    const float* ln2b   = (const float*)d_in[14];
    const float* w1     = (const float*)d_in[15];
    const float* b1     = (const float*)d_in[16];
    const float* w2     = (const float*)d_in[17];
    const float* b2     = (const float*)d_in[18];
    const float* pw     = (const float*)d_in[19];
    const float* pb     = (const float*)d_in[20];
    const float* projs  = (const float*)d_in[21];
    float* out = (float*)d_out;

    float* ws = nullptr;
    if (ws_size >= WS_FLOATS * sizeof(float)) {
        ws = (float*)d_ws;
    } else {
        void* p = nullptr;
        hipGetSymbolAddress(&p, HIP_SYMBOL(g_ws));   // pure query, capture-safe
        ws = (float*)p;
    }

    float* x = ws;                                      // fp32 [NRP][256]
    unsigned short* hb = (unsigned short*)(x + SZP_);   // bf16 [NRP][256]
    unsigned short* qkvb = hb + (size_t)NRP_ * D_;      // bf16 [NRP][768]
    unsigned short* interb = qkvb + (size_t)NRP_ * QS_; // bf16 [NRP][1024]
    unsigned short* wqkvT = interb + (size_t)NRP_ * FF_;    // [6][768][256]
    unsigned short* woT = wqkvT + (size_t)L_ * QS_ * D_;    // [6][256][256]
    unsigned short* w1T = woT + (size_t)L_ * D_ * D_;       // [6][1024][256]
    unsigned short* w2T = w1T + (size_t)L_ * D_ * FF_;      // [6][256][1024]
    float* bqkv  = (float*)(w2T + (size_t)L_ * FF_ * D_);   // [6][768]
    float* ebuf  = bqkv + L_ * QS_ + 32;
    float* ssum  = ebuf + B_ * G_;
    unsigned* maxkey = (unsigned*)(ssum + 8);
    unsigned* stab   = maxkey + 8;
    float* kfsum = (float*)(stab + 8);                 // [BH_][M_]
    float* ctx   = kfsum + BH_ * M_ + 32;              // [BH_][M_][DH_]

    // weights: transpose + bf16 convert (QKV packed into [768][256] per layer)
    dim3 wb(32, 8);
    k_wconv<<<dim3(D_ / 32, D_ / 32, L_), wb, 0, stream>>>(wq, wqkvT,            D_, D_, QS_ * D_);
    k_wconv<<<dim3(D_ / 32, D_ / 32, L_), wb, 0, stream>>>(wk, wqkvT + 256 * D_, D_, D_, QS_ * D_);
    k_wconv<<<dim3(D_ / 32, D_ / 32, L_), wb, 0, stream>>>(wv, wqkvT + 512 * D_, D_, D_, QS_ * D_);
    k_wconv<<<dim3(D_ / 32, D_ / 32, L_), wb, 0, stream>>>(wo, woT, D_, D_, D_ * D_);
    k_wconv<<<dim3(FF_ / 32, D_ / 32, L_), wb, 0, stream>>>(w1, w1T, D_, FF_, D_ * FF_);
    k_wconv<<<dim3(D_ / 32, FF_ / 32, L_), wb, 0, stream>>>(w2, w2T, FF_, D_, FF_ * D_);
    k_packbias<<<L_, 256, 0, stream>>>(bq, bk, bv, bqkv);

    // preprocess
    k_pre_init<<<1, 64, 0, stream>>>(maxkey);
    k_rowsum<<<B_, 256, 0, stream>>>(expr, ssum);
    k_compute_e<<<(B_ * G_ + 255) / 256, 256, 0, stream>>>(expr, ssum, ebuf, maxkey);
    k_embed<<<NRP_, 256, 0, stream>>>(ebuf, maxkey, tokemb, cls, x);

    const int NYC = (NYT_ + 7) / 8;              // 67
    int gQKV = 8 * NYC * (QS_ / 128);            // 3216
    int gWO  = 8 * NYC * (D_ / 128);             // 1072
    int gF1  = 8 * NYC * (FF_ / 128);            // 4288
    int gF2  = 8 * NYC * (D_ / 128);             // 1072
    dim3 gBH((NSEQ + 255) / 256, 32);            // (67, 32)

    for (int l = 0; l < L_; ++l){
        const float* pjl = projs + (size_t)l * M_ * DH_;
        k_ln<<<NRP_, 256, 0, stream>>>(x, hb, ln1g + l * D_, ln1b + l * D_);
        gemm_bf16<3><<<gQKV, 256, 0, stream>>>(hb, wqkvT + (size_t)l * QS_ * D_, bqkv + l * QS_,
                                               nullptr, qkvb, D_, QS_, NYT_);
        k_layer_init<<<64, 256, 0, stream>>>(kfsum, ctx, stab);
        k_kmax<<<gBH, 256, 0, stream>>>(qkvb, pjl, stab);
        k_kv<<<gBH, 256, 0, stream>>>(qkvb, pjl, stab, kfsum, ctx);
        k_qattn<<<gBH, 256, 0, stream>>>(qkvb, pjl, kfsum, ctx, hb);   // hb := attn out
        gemm_bf16<1><<<gWO, 256, 0, stream>>>(hb, woT + (size_t)l * D_ * D_, bo + l * D_,
                                              x, nullptr, D_, D_, NYT_);
        k_ln<<<NRP_, 256, 0, stream>>>(x, hb, ln2g + l * D_, ln2b + l * D_);
        gemm_bf16<2><<<gF1, 256, 0, stream>>>(hb, w1T + (size_t)l * D_ * FF_, b1 + l * FF_,
                                              nullptr, interb, D_, FF_, NYT_);
        gemm_bf16<1><<<gF2, 256, 0, stream>>>(interb, w2T + (size_t)l * FF_ * D_, b2 + l * D_,
                                              x, nullptr, FF_, D_, NYT_);
    }
    k_final<<<B_, 256, 0, stream>>>(x, pw, pb, out);
}

// Round 15
// 4845.585 us; speedup vs baseline: 1.0957x; 1.0957x over previous
//
#include <hip/hip_runtime.h>
#include <math.h>

#define B_ 4
#define G_ 16906
#define D_ 256
#define H_ 8
#define DH_ 32
#define M_ 110
#define L_ 6
#define FF_ 1024
#define NSEQ (G_ + 1)          // 16907
#define NR (B_ * NSEQ)         // 67628
#define NRP_ 67712             // 529*128, row-padded for 128-tiles
#define NYT_ 529               // row tiles
#define BH_ 32                 // B_*H_
#define QS_ 768                // fused qkv row stride (q:0, k:256, v:512)

static constexpr float SCALE_  = 0.42044820762685725f;   // 32^-0.25
static constexpr float MSCALE_ = 0.09534625892455922f;   // 110^-0.5
static constexpr float FEPS_   = 1e-4f;

// ---- static workspace (module-load-time allocation; R1 proved d_ws too small) ----
#define SZP_ ((size_t)NRP_ * D_)                 // fp32 x buffer
#define WS_FLOATS 92000000                       // ~368 MB
__device__ float g_ws[WS_FLOATS];

typedef __attribute__((ext_vector_type(8))) short bh8;   // 8 bf16 (4 VGPR)
typedef __attribute__((ext_vector_type(4))) float f4;    // MFMA acc

// ---- helpers ----
__device__ __forceinline__ unsigned f2u(float f){
    unsigned u = __float_as_uint(f);
    return (u & 0x80000000u) ? ~u : (u | 0x80000000u);
}
__device__ __forceinline__ float u2f(unsigned u){
    return (u & 0x80000000u) ? __uint_as_float(u & 0x7fffffffu) : __uint_as_float(~u);
}
__device__ __forceinline__ unsigned short f2b(float f){   // fp32 -> bf16 RNE
    unsigned u = __float_as_uint(f);
    return (unsigned short)((u + 0x7fffu + ((u >> 16) & 1u)) >> 16);
}
__device__ __forceinline__ float bf2f(unsigned short u){
    return __uint_as_float(((unsigned)u) << 16);
}

// =============== preprocess ===============
__global__ void k_pre_init(unsigned* __restrict__ maxkey){
    if (threadIdx.x == 0) *maxkey = 0x007fffffu;  // f2u(-inf)
}

__global__ void k_rowsum(const float* __restrict__ expr, float* __restrict__ ssum){
    int b = blockIdx.x, t = threadIdx.x;
    float s = 0.f;
    for (int g = t; g < G_; g += 256) s += fabsf(expr[(size_t)b * G_ + g]);
    __shared__ float red[256];
    red[t] = s; __syncthreads();
    for (int off = 128; off > 0; off >>= 1){ if (t < off) red[t] += red[t + off]; __syncthreads(); }
    if (t == 0) ssum[b] = red[0];
}

__global__ void k_compute_e(const float* __restrict__ expr, const float* __restrict__ ssum,
                            float* __restrict__ ebuf, unsigned* __restrict__ maxkey){
    int t = threadIdx.x;
    int idx = blockIdx.x * 256 + t;
    float e = -INFINITY;
    if (idx < B_ * G_){
        int b = idx / G_;
        float denom = fmaxf(ssum[b], 1e-12f);
        e = log1pf(expr[idx] / denom * 1e4f);
        ebuf[idx] = e;
    }
    __shared__ float red[256];
    red[t] = e; __syncthreads();
    for (int off = 128; off > 0; off >>= 1){ if (t < off) red[t] = fmaxf(red[t], red[t + off]); __syncthreads(); }
    if (t == 0) atomicMax(maxkey, f2u(red[0]));
}

__global__ void k_embed(const float* __restrict__ ebuf, const unsigned* __restrict__ maxkey,
                        const float* __restrict__ tokemb, const float* __restrict__ cls,
                        float* __restrict__ x){
    int row = blockIdx.x, t = threadIdx.x;
    if (row >= NR){ x[(size_t)row * D_ + t] = 0.f; return; }   // pad rows -> 0
    int b = row / NSEQ, i = row % NSEQ;
    float v;
    if (i == 0){
        v = cls[t];
    } else {
        float e = ebuf[(size_t)b * G_ + (i - 1)];
        float mx = u2f(*maxkey);
        float step = mx / 7.0f;                 // linspace(0,mx,8)[:7] = step*j
        int cnt = 0;
        #pragma unroll
        for (int j = 0; j < 7; ++j){
            float bin = step * (float)j;
            cnt += (bin < e) ? 1 : 0;           // searchsorted side='left'
        }
        if (cnt > 6) cnt = 6;
        v = tokemb[cnt * D_ + t];
    }
    x[(size_t)row * D_ + t] = v;
}

// =============== layernorm: fp32 in, bf16 out ===============
// R15: one 64-lane wave per row (4 elems/lane), shuffle-reduce — no barriers,
// no LDS (was: 1 block/row with 6 __syncthreads). 4 rows/block.
__launch_bounds__(256)
__global__ void k_ln(const float* __restrict__ X, unsigned short* __restrict__ Y,
                     const float* __restrict__ g, const float* __restrict__ b){
    int wave = threadIdx.x >> 6, lane = threadIdx.x & 63;
    int row = blockIdx.x * 4 + wave;
    float4 v = *(const float4*)&X[(size_t)row * D_ + lane * 4];
    float s = v.x + v.y + v.z + v.w;
    s += __shfl_xor(s, 1);  s += __shfl_xor(s, 2);  s += __shfl_xor(s, 4);
    s += __shfl_xor(s, 8);  s += __shfl_xor(s, 16); s += __shfl_xor(s, 32);
    float mu = s * (1.0f / 256.0f);
    float d0 = v.x - mu, d1 = v.y - mu, d2 = v.z - mu, d3 = v.w - mu;
    float q = d0 * d0 + d1 * d1 + d2 * d2 + d3 * d3;
    q += __shfl_xor(q, 1);  q += __shfl_xor(q, 2);  q += __shfl_xor(q, 4);
    q += __shfl_xor(q, 8);  q += __shfl_xor(q, 16); q += __shfl_xor(q, 32);
    float inv = rsqrtf(q * (1.0f / 256.0f) + 1e-5f);
    float4 gv = *(const float4*)&g[lane * 4];
    float4 bv = *(const float4*)&b[lane * 4];
    ushort4 o;
    o.x = f2b(d0 * inv * gv.x + bv.x);
    o.y = f2b(d1 * inv * gv.y + bv.y);
    o.z = f2b(d2 * inv * gv.z + bv.z);
    o.w = f2b(d3 * inv * gv.w + bv.w);
    *(ushort4*)&Y[(size_t)row * D_ + lane * 4] = o;
}

// =============== weight transpose + bf16 convert: Wout[n][k] = Win[k][n] ===============
__global__ void k_wconv(const float* __restrict__ Win, unsigned short* __restrict__ Wout,
                        int K, int N, int lstride){
    __shared__ float tile[32][33];
    int l = blockIdx.z;
    const float* W = Win + (size_t)l * K * N;
    unsigned short* O = Wout + (size_t)l * lstride;
    int n0 = blockIdx.x * 32, k0 = blockIdx.y * 32;
    int tx = threadIdx.x, ty = threadIdx.y;
    #pragma unroll
    for (int j = 0; j < 4; ++j)
        tile[ty + j * 8][tx] = W[(size_t)(k0 + ty + j * 8) * N + n0 + tx];
    __syncthreads();
    #pragma unroll
    for (int j = 0; j < 4; ++j){
        int n = ty + j * 8;
        O[(size_t)(n0 + n) * K + k0 + tx] = f2b(tile[tx][n]);
    }
}

__global__ void k_packbias(const float* __restrict__ bq, const float* __restrict__ bk,
                           const float* __restrict__ bv, float* __restrict__ o){
    int l = blockIdx.x, t = threadIdx.x;
    o[l * QS_ + t]        = bq[l * D_ + t];
    o[l * QS_ + 256 + t]  = bk[l * D_ + t];
    o[l * QS_ + 512 + t]  = bv[l * D_ + t];
}

// =============== bf16 MFMA GEMM: C = op(A @ Wt^T + bias) ===============
// MODE 0: Cf = A@W + bias (fp32)        MODE 1: Cf += A@W + bias (fp32 residual)
// MODE 2: Cb = bf16(gelu(A@W + bias))   MODE 3: Cb = bf16(A@W + bias)
// R12 XCD swizzle + R11 pipelined K-loop + R8 LDS bf16 epilogue.
// (R13: FFN fusion regressed — L2 thrash. R14: inline-diag regressed — reverted.)
#define GP 40
#define EPIT 136
#define BUFSZ (2 * 128 * GP)   // one A+B pair (shorts)
template <int MODE>
__launch_bounds__(256)
__global__ void gemm_bf16(const unsigned short* __restrict__ A,
                          const unsigned short* __restrict__ Wt,
                          const float* __restrict__ bias,
                          float* __restrict__ Cf, unsigned short* __restrict__ Cb,
                          int K, int N, int NY){
    int NX = N >> 7;
    int lid = blockIdx.x;
    int xcd = lid & 7, slot = lid >> 3;
    int colt = slot % NX;
    int rowt = (slot / NX) * 8 + xcd;
    if (rowt >= NY) return;
    int rowBase = rowt * 128, colBase = colt * 128;

    __shared__ __align__(16) unsigned short smem[2 * BUFSZ];
    int tid = threadIdx.x;
    int lane = tid & 63, wave = tid >> 6;
    int wrow = (wave >> 1) * 64, wcol = (wave & 1) * 64;
    int srow = tid >> 2, sslot = tid & 3;
    int m = lane & 15, kg = lane >> 4;
    int sOff = srow * GP + sslot * 8;

    f4 acc[4][4];
    #pragma unroll
    for (int i = 0; i < 4; ++i)
        #pragma unroll
        for (int j = 0; j < 4; ++j) acc[i][j] = (f4){0.f, 0.f, 0.f, 0.f};

    const unsigned short* Ag = A + (size_t)(rowBase + srow) * K + sslot * 8;
    const unsigned short* Bg = Wt + (size_t)(colBase + srow) * K + sslot * 8;

    {
        uint4 a0 = *(const uint4*)(Ag);
        uint4 a1 = *(const uint4*)(Ag + (size_t)64 * K);
        uint4 b0 = *(const uint4*)(Bg);
        uint4 b1 = *(const uint4*)(Bg + (size_t)64 * K);
        *(uint4*)&smem[sOff] = a0;
        *(uint4*)&smem[64 * GP + sOff] = a1;
        *(uint4*)&smem[128 * GP + sOff] = b0;
        *(uint4*)&smem[128 * GP + 64 * GP + sOff] = b1;
    }
    const int NIT = K >> 5;
    for (int it = 0; it < NIT; ++it){
        __syncthreads();
        int cur = (it & 1) * BUFSZ;
        uint4 na0, na1, nb0, nb1;
        bool more = (it + 1 < NIT);
        if (more){
            int k0 = (it + 1) << 5;
            na0 = *(const uint4*)(Ag + k0);
            na1 = *(const uint4*)(Ag + (size_t)64 * K + k0);
            nb0 = *(const uint4*)(Bg + k0);
            nb1 = *(const uint4*)(Bg + (size_t)64 * K + k0);
        }
        bh8 af[4], bf[4];
        #pragma unroll
        for (int mi = 0; mi < 4; ++mi)
            af[mi] = *(const bh8*)&smem[cur + (wrow + mi * 16 + m) * GP + kg * 8];
        #pragma unroll
        for (int ni = 0; ni < 4; ++ni)
            bf[ni] = *(const bh8*)&smem[cur + 128 * GP + (wcol + ni * 16 + m) * GP + kg * 8];
        #pragma unroll
        for (int mi = 0; mi < 4; ++mi)
            #pragma unroll
            for (int ni = 0; ni < 4; ++ni)
                acc[mi][ni] = __builtin_amdgcn_mfma_f32_16x16x32_bf16(af[mi], bf[ni], acc[mi][ni], 0, 0, 0);
        if (more){
            int nxt = ((it + 1) & 1) * BUFSZ;
            *(uint4*)&smem[nxt + sOff] = na0;
            *(uint4*)&smem[nxt + 64 * GP + sOff] = na1;
            *(uint4*)&smem[nxt + 128 * GP + sOff] = nb0;
            *(uint4*)&smem[nxt + 128 * GP + 64 * GP + sOff] = nb1;
        }
    }
    __syncthreads();
    int q4 = lane >> 4;
    if (MODE == 0 || MODE == 1){
        #pragma unroll
        for (int ni = 0; ni < 4; ++ni){
            int col = colBase + wcol + ni * 16 + m;
            float bv = bias[col];
            #pragma unroll
            for (int mi = 0; mi < 4; ++mi){
                int r0 = rowBase + wrow + mi * 16 + q4 * 4;
                #pragma unroll
                for (int rg = 0; rg < 4; ++rg){
                    int row = r0 + rg;
                    float v = acc[mi][ni][rg] + bv;
                    if (MODE == 1) v += Cf[(size_t)row * N + col];
                    Cf[(size_t)row * N + col] = v;
                }
            }
        }
    } else {
        #pragma unroll
        for (int half = 0; half < 2; ++half){
            if ((wrow >> 6) == half){
                #pragma unroll
                for (int ni = 0; ni < 4; ++ni){
                    int coll = wcol + ni * 16 + m;
                    float bv = bias[colBase + coll];
                    #pragma unroll
                    for (int mi = 0; mi < 4; ++mi){
                        int rl0 = (wrow & 63) + mi * 16 + q4 * 4;
                        #pragma unroll
                        for (int rg = 0; rg < 4; ++rg){
                            float v = acc[mi][ni][rg] + bv;
                            if (MODE == 2) v = 0.5f * v * (1.0f + erff(v * 0.70710678118654752f));
                            smem[(rl0 + rg) * EPIT + coll] = f2b(v);
                        }
                    }
                }
            }
            __syncthreads();
            #pragma unroll
            for (int p = 0; p < 4; ++p){
                int idx = p * 256 + tid;
                int r = idx >> 4, ch = idx & 15;
                int grow = rowBase + half * 64 + r;
                uint4 val = *(const uint4*)&smem[r * EPIT + ch * 8];
                *(uint4*)&Cb[(size_t)grow * N + colBase + ch * 8] = val;
            }
            __syncthreads();
        }
    }
}

// =============== attention state init ===============
__global__ void k_layer_init(float* __restrict__ kfsum, float* __restrict__ ctx,
                             unsigned* __restrict__ stab){
    int t = blockIdx.x * 256 + threadIdx.x;
    int nt = gridDim.x * 256;
    if (t == 0) *stab = 0x007fffffu;  // f2u(-inf)
    for (int i = t; i < BH_ * M_; i += nt) kfsum[i] = 0.f;
    for (int i = t; i < BH_ * M_ * DH_; i += nt) ctx[i] = 0.f;
}

// =============== diag from fused qkv buffer ===============
__global__ void k_diag(const unsigned short* __restrict__ qkv,
                       float* __restrict__ diagq, float* __restrict__ diagk){
    int idx = blockIdx.x * 256 + threadIdx.x;   // over NR*8
    if (idx >= NR * 8) return;
    int row = idx >> 3, h = idx & 7;
    const unsigned short* qp = qkv + (size_t)row * QS_ + h * DH_;
    const unsigned short* kp = qkv + (size_t)row * QS_ + 256 + h * DH_;
    float sq = 0.f, sk = 0.f;
    #pragma unroll
    for (int d = 0; d < DH_; ++d){
        float qv = bf2f(qp[d]) * SCALE_; sq += qv * qv;
        float kv = bf2f(kp[d]) * SCALE_; sk += kv * kv;
    }
    diagq[idx] = 0.5f * sq;
    diagk[idx] = 0.5f * sk;
}

// =============== k_kmax: global max of dd (K-side) via MFMA ===============
__launch_bounds__(256)
__global__ void k_kmax(const unsigned short* __restrict__ qkv, const float* __restrict__ proj,
                       unsigned* __restrict__ stab){
    __shared__ __align__(16) unsigned short pjT[112 * 40];
    __shared__ __align__(16) unsigned short kl[32 * 40];
    __shared__ float red[256];
    int t = threadIdx.x, lane = t & 63, wave = t >> 6;
    int m16 = lane & 15, quad = lane >> 4;
    int bh = blockIdx.y, b = bh >> 3, hh = bh & 7;
    for (int e = t; e < 112 * 32; e += 256){
        int mm = e >> 5, d = e & 31;
        pjT[mm * 40 + d] = f2b((mm < M_) ? SCALE_ * proj[mm * DH_ + d] : 0.f);
    }
    int i0 = blockIdx.x * 256, i1 = min(i0 + 256, NSEQ);
    float mx = -INFINITY;
    __syncthreads();
    for (int t0 = i0; t0 < i1; t0 += 32){
        int rows = min(32, i1 - t0);
        for (int e = t; e < 32 * 32; e += 256){
            int i = e >> 5, d = e & 31;
            unsigned short v = 0;
            if (i < rows) v = qkv[((size_t)(b * NSEQ + t0 + i)) * QS_ + 256 + hh * DH_ + d];
            kl[i * 40 + d] = v;
        }
        __syncthreads();
        #pragma unroll
        for (int nn = 0; nn < 2; ++nn){
            int nt = wave + nn * 4;
            if (nt >= 7) continue;
            bh8 bfrag = *(const bh8*)&pjT[(nt * 16 + m16) * 40 + quad * 8];
            int f = nt * 16 + m16;
            #pragma unroll
            for (int mt = 0; mt < 2; ++mt){
                bh8 afrag = *(const bh8*)&kl[(mt * 16 + m16) * 40 + quad * 8];
                f4 dd = (f4){0.f,0.f,0.f,0.f};
                dd = __builtin_amdgcn_mfma_f32_16x16x32_bf16(afrag, bfrag, dd, 0, 0, 0);
                #pragma unroll
                for (int rg = 0; rg < 4; ++rg){
                    int r = mt * 16 + quad * 4 + rg;
                    if (f < M_ && r < rows) mx = fmaxf(mx, dd[rg]);
                }
            }
        }
        __syncthreads();
    }
    red[t] = mx; __syncthreads();
    for (int off = 128; off > 0; off >>= 1){ if (t < off) red[t] = fmaxf(red[t], red[t + off]); __syncthreads(); }
    if (t == 0) atomicMax(stab, f2u(red[0]));
}

// =============== k_kv: kf via dd-MFMA, ctx += kf^T @ V via MFMA ===============
__launch_bounds__(256)
__global__ void k_kv(const unsigned short* __restrict__ qkv,
                     const float* __restrict__ proj, const float* __restrict__ diagk,
                     const unsigned* __restrict__ stabkey,
                     float* __restrict__ kfsum, float* __restrict__ ctx){
    __shared__ __align__(16) unsigned short pjT[112 * 40];
    __shared__ __align__(16) unsigned short kl[32 * 40];
    __shared__ __align__(16) unsigned short vT[32 * 40];
    __shared__ __align__(16) unsigned short kfT[112 * 40];
    __shared__ float diagl[32];
    int t = threadIdx.x, lane = t & 63, wave = t >> 6;
    int m16 = lane & 15, quad = lane >> 4;
    int bh = blockIdx.y, b = bh >> 3, hh = bh & 7;
    for (int e = t; e < 112 * 32; e += 256){
        int mm = e >> 5, d = e & 31;
        pjT[mm * 40 + d] = f2b((mm < M_) ? SCALE_ * proj[mm * DH_ + d] : 0.f);
    }
    float stab = u2f(*stabkey);
    f4 acc[2][2];
    #pragma unroll
    for (int i = 0; i < 2; ++i)
        #pragma unroll
        for (int j = 0; j < 2; ++j) acc[i][j] = (f4){0.f,0.f,0.f,0.f};
    float ksum = 0.f;
    int i0 = blockIdx.x * 256, i1 = min(i0 + 256, NSEQ);
    __syncthreads();
    for (int t0 = i0; t0 < i1; t0 += 32){
        int rows = min(32, i1 - t0);
        for (int e = t; e < 32 * 32; e += 256){
            int i = e >> 5, d = e & 31;
            unsigned short kvv = 0, vvv = 0;
            if (i < rows){
                size_t base = ((size_t)(b * NSEQ + t0 + i)) * QS_ + hh * DH_ + d;
                kvv = qkv[base + 256]; vvv = qkv[base + 512];
            }
            kl[i * 40 + d] = kvv;
            vT[d * 40 + i] = vvv;
        }
        if (t < 32) diagl[t] = (t < rows) ? diagk[((size_t)(b * NSEQ + t0 + t)) * 8 + hh] : 0.f;
        __syncthreads();
        #pragma unroll
        for (int nn = 0; nn < 2; ++nn){
            int nt = wave + nn * 4;
            if (nt >= 7) continue;
            bh8 bfrag = *(const bh8*)&pjT[(nt * 16 + m16) * 40 + quad * 8];
            int f = nt * 16 + m16;
            #pragma unroll
            for (int mt = 0; mt < 2; ++mt){
                bh8 afrag = *(const bh8*)&kl[(mt * 16 + m16) * 40 + quad * 8];
                f4 dd = (f4){0.f,0.f,0.f,0.f};
                dd = __builtin_amdgcn_mfma_f32_16x16x32_bf16(afrag, bfrag, dd, 0, 0, 0);
                #pragma unroll
                for (int rg = 0; rg < 4; ++rg){
                    int r = mt * 16 + quad * 4 + rg;
                    float kf = 0.f;
                    if (r < rows) kf = MSCALE_ * (__expf(dd[rg] - diagl[r] - stab) + FEPS_);
                    kfT[f * 40 + r] = f2b(kf);
                }
            }
        }
        __syncthreads();
        #pragma unroll
        for (int mm = 0; mm < 2; ++mm){
            int mt = wave + mm * 4;
            if (mt >= 7) continue;
            bh8 afrag = *(const bh8*)&kfT[(mt * 16 + m16) * 40 + quad * 8];
            #pragma unroll
            for (int nt2 = 0; nt2 < 2; ++nt2){
                bh8 bfrag = *(const bh8*)&vT[(nt2 * 16 + m16) * 40 + quad * 8];
                acc[mm][nt2] = __builtin_amdgcn_mfma_f32_16x16x32_bf16(afrag, bfrag, acc[mm][nt2], 0, 0, 0);
            }
        }
        if (t < M_){
            for (int i = 0; i < rows; ++i) ksum += bf2f(kfT[t * 40 + i]);
        }
        __syncthreads();
    }
    float* ctx_bh = ctx + (size_t)bh * M_ * DH_;
    #pragma unroll
    for (int mm = 0; mm < 2; ++mm){
        int mt = wave + mm * 4;
        if (mt >= 7) continue;
        #pragma unroll
        for (int nt2 = 0; nt2 < 2; ++nt2){
            #pragma unroll
            for (int rg = 0; rg < 4; ++rg){
                int f = mt * 16 + quad * 4 + rg;
                int dh = nt2 * 16 + m16;
                if (f < M_) atomicAdd(&ctx_bh[f * DH_ + dh], acc[mm][nt2][rg]);
            }
        }
    }
    if (t < M_) atomicAdd(&kfsum[bh * M_ + t], ksum);
}

// =============== k_qattn: qf via dd-MFMA (rowmax), o = qf @ ctx via MFMA ===============
#define CXP 136
__launch_bounds__(256)
__global__ void k_qattn(const unsigned short* __restrict__ qkv, const float* __restrict__ proj,
                        const float* __restrict__ diagq, const float* __restrict__ kfsumg,
                        const float* __restrict__ ctxg, unsigned short* __restrict__ Ob){
    __shared__ __align__(16) unsigned short pjT[112 * 40];
    __shared__ __align__(16) unsigned short ql[32 * 40];
    __shared__ __align__(16) unsigned short qfl[32 * CXP];
    __shared__ __align__(16) unsigned short cxT[32 * CXP];
    __shared__ float kfs[112];
    __shared__ float diagl[32];
    __shared__ float rmax[4][32];
    __shared__ float denl[32];
    int t = threadIdx.x, lane = t & 63, wave = t >> 6;
    int m16 = lane & 15, quad = lane >> 4;
    int bh = blockIdx.y, b = bh >> 3, hh = bh & 7;
    const float* ctx_bh = ctxg + (size_t)bh * M_ * DH_;
    for (int e = t; e < 112 * 32; e += 256){
        int mm = e >> 5, d = e & 31;
        pjT[mm * 40 + d] = f2b((mm < M_) ? SCALE_ * proj[mm * DH_ + d] : 0.f);
    }
    for (int e = t; e < 32 * 128; e += 256){
        int dh = e >> 7, f = e & 127;
        cxT[dh * CXP + f] = f2b((f < M_) ? ctx_bh[f * DH_ + dh] : 0.f);
    }
    for (int e = t; e < 32 * CXP; e += 256) qfl[e] = 0;
    if (t < M_) kfs[t] = kfsumg[bh * M_ + t];
    int i0 = blockIdx.x * 256, i1 = min(i0 + 256, NSEQ);
    __syncthreads();
    for (int t0 = i0; t0 < i1; t0 += 32){
        int rows = min(32, i1 - t0);
        for (int e = t; e < 32 * 32; e += 256){
            int i = e >> 5, d = e & 31;
            unsigned short v = 0;
            if (i < rows) v = qkv[((size_t)(b * NSEQ + t0 + i)) * QS_ + hh * DH_ + d];
            ql[i * 40 + d] = v;
        }
        if (t < 32) diagl[t] = (t < rows) ? diagq[((size_t)(b * NSEQ + t0 + t)) * 8 + hh] : 0.f;
        __syncthreads();
        f4 ddv[2][2];
        float pm[2][4];
        #pragma unroll
        for (int mt = 0; mt < 2; ++mt)
            #pragma unroll
            for (int rg = 0; rg < 4; ++rg) pm[mt][rg] = -INFINITY;
        #pragma unroll
        for (int nn = 0; nn < 2; ++nn){
            int nt = wave + nn * 4;
            if (nt >= 7) continue;
            bh8 bfrag = *(const bh8*)&pjT[(nt * 16 + m16) * 40 + quad * 8];
            int f = nt * 16 + m16;
            #pragma unroll
            for (int mt = 0; mt < 2; ++mt){
                bh8 afrag = *(const bh8*)&ql[(mt * 16 + m16) * 40 + quad * 8];
                f4 dd = (f4){0.f,0.f,0.f,0.f};
                dd = __builtin_amdgcn_mfma_f32_16x16x32_bf16(afrag, bfrag, dd, 0, 0, 0);
                ddv[nn][mt] = dd;
                if (f < M_){
                    #pragma unroll
                    for (int rg = 0; rg < 4; ++rg) pm[mt][rg] = fmaxf(pm[mt][rg], dd[rg]);
                }
            }
        }
        #pragma unroll
        for (int mt = 0; mt < 2; ++mt)
            #pragma unroll
            for (int rg = 0; rg < 4; ++rg){
                float v = pm[mt][rg];
                v = fmaxf(v, __shfl_xor(v, 1));
                v = fmaxf(v, __shfl_xor(v, 2));
                v = fmaxf(v, __shfl_xor(v, 4));
                v = fmaxf(v, __shfl_xor(v, 8));
                if (m16 == 0) rmax[wave][mt * 16 + quad * 4 + rg] = v;
            }
        __syncthreads();
        #pragma unroll
        for (int nn = 0; nn < 2; ++nn){
            int nt = wave + nn * 4;
            if (nt >= 7) continue;
            int f = nt * 16 + m16;
            #pragma unroll
            for (int mt = 0; mt < 2; ++mt){
                #pragma unroll
                for (int rg = 0; rg < 4; ++rg){
                    int r = mt * 16 + quad * 4 + rg;
                    float mx = fmaxf(fmaxf(rmax[0][r], rmax[1][r]), fmaxf(rmax[2][r], rmax[3][r]));
                    float qf = MSCALE_ * (__expf(ddv[nn][mt][rg] - diagl[r] - mx) + FEPS_);
                    qfl[r * CXP + f] = f2b(qf);
                }
            }
        }
        __syncthreads();
        {
            int r = t >> 3, part = t & 7;
            float s = 0.f;
            for (int f = part; f < M_; f += 8) s += bf2f(qfl[r * CXP + f]) * kfs[f];
            s += __shfl_xor(s, 4); s += __shfl_xor(s, 2); s += __shfl_xor(s, 1);
            if (part == 0) denl[r] = s;
        }
        __syncthreads();
        {
            int mt = wave >> 1, nt = wave & 1;
            f4 oacc = (f4){0.f,0.f,0.f,0.f};
            #pragma unroll
            for (int kk = 0; kk < 4; ++kk){
                bh8 afrag = *(const bh8*)&qfl[(mt * 16 + m16) * CXP + kk * 32 + quad * 8];
                bh8 bfrag = *(const bh8*)&cxT[(nt * 16 + m16) * CXP + kk * 32 + quad * 8];
                oacc = __builtin_amdgcn_mfma_f32_16x16x32_bf16(afrag, bfrag, oacc, 0, 0, 0);
            }
            #pragma unroll
            for (int rg = 0; rg < 4; ++rg){
                int r = mt * 16 + quad * 4 + rg;
                if (r < rows){
                    int grow = b * NSEQ + t0 + r;
                    float o = oacc[rg] / denl[r];
                    Ob[(size_t)grow * D_ + hh * DH_ + nt * 16 + m16] = f2b(o);
                }
            }
        }
        __syncthreads();
    }
}

// =============== final projection: out[b] = x[b,0] @ pw + pb (fp32) ===============
__global__ void k_final(const float* __restrict__ x, const float* __restrict__ pw,
                        const float* __restrict__ pb, float* __restrict__ out){
    int b = blockIdx.x, c = threadIdx.x;
    const float* xr = x + (size_t)b * NSEQ * D_;
    float s = pb[c];
    for (int k = 0; k < D_; ++k) s += xr[k] * pw[k * D_ + c];
    out[b * D_ + c] = s;
}

// =============== host launcher ===============
extern "C" void kernel_launch(void* const* d_in, const int* in_sizes, int n_in,
                              void* d_out, int out_size, void* d_ws, size_t ws_size,
                              hipStream_t stream){
    const float* expr   = (const float*)d_in[0];
    const float* tokemb = (const float*)d_in[1];
    const float* cls    = (const float*)d_in[2];
    const float* ln1g   = (const float*)d_in[3];
    const float* ln1b   = (const float*)d_in[4];
    const float* wq     = (const float*)d_in[5];
    const float* bq     = (const float*)d_in[6];
    const float* wk     = (const float*)d_in[7];
    const float* bk     = (const float*)d_in[8];
    const float* wv     = (const float*)d_in[9];
    const float* bv     = (const float*)d_in[10];
    const float* wo     = (const float*)d_in[11];
    const float* bo     = (const float*)d_in[12];
    const float* ln2g   = (const float*)d_in[13];
    const float* ln2b   = (const float*)d_in[14];
    const float* w1     = (const float*)d_in[15];
    const float* b1     = (const float*)d_in[16];
    const float* w2     = (const float*)d_in[17];
    const float* b2     = (const float*)d_in[18];
    const float* pw     = (const float*)d_in[19];
    const float* pb     = (const float*)d_in[20];
    const float* projs  = (const float*)d_in[21];
    float* out = (float*)d_out;

    float* ws = nullptr;
    if (ws_size >= WS_FLOATS * sizeof(float)) {
        ws = (float*)d_ws;
    } else {
        void* p = nullptr;
        hipGetSymbolAddress(&p, HIP_SYMBOL(g_ws));   // pure query, capture-safe
        ws = (float*)p;
    }

    float* x = ws;                                      // fp32 [NRP][256]
    unsigned short* hb = (unsigned short*)(x + SZP_);   // bf16 [NRP][256]
    unsigned short* qkvb = hb + (size_t)NRP_ * D_;      // bf16 [NRP][768]
    unsigned short* interb = qkvb + (size_t)NRP_ * QS_; // bf16 [NRP][1024]
    unsigned short* wqkvT = interb + (size_t)NRP_ * FF_;    // [6][768][256]
    unsigned short* woT = wqkvT + (size_t)L_ * QS_ * D_;    // [6][256][256]
    unsigned short* w1T = woT + (size_t)L_ * D_ * D_;       // [6][1024][256]
    unsigned short* w2T = w1T + (size_t)L_ * D_ * FF_;      // [6][256][1024]
    float* bqkv  = (float*)(w2T + (size_t)L_ * FF_ * D_);   // [6][768]
    float* diagq = bqkv + L_ * QS_ + 32;
    float* diagk = diagq + (size_t)NR * 8 + 32;
    float* ebuf  = diagk + (size_t)NR * 8 + 32;
    float* ssum  = ebuf + B_ * G_;
    unsigned* maxkey = (unsigned*)(ssum + 8);
    unsigned* stab   = maxkey + 8;
    float* kfsum = (float*)(stab + 8);                 // [BH_][M_]
    float* ctx   = kfsum + BH_ * M_ + 32;              // [BH_][M_][DH_]

    // weights: transpose + bf16 convert (QKV packed into [768][256] per layer)
    dim3 wb(32, 8);
    k_wconv<<<dim3(D_ / 32, D_ / 32, L_), wb, 0, stream>>>(wq, wqkvT,            D_, D_, QS_ * D_);
    k_wconv<<<dim3(D_ / 32, D_ / 32, L_), wb, 0, stream>>>(wk, wqkvT + 256 * D_, D_, D_, QS_ * D_);
    k_wconv<<<dim3(D_ / 32, D_ / 32, L_), wb, 0, stream>>>(wv, wqkvT + 512 * D_, D_, D_, QS_ * D_);
    k_wconv<<<dim3(D_ / 32, D_ / 32, L_), wb, 0, stream>>>(wo, woT, D_, D_, D_ * D_);
    k_wconv<<<dim3(FF_ / 32, D_ / 32, L_), wb, 0, stream>>>(w1, w1T, D_, FF_, D_ * FF_);
    k_wconv<<<dim3(D_ / 32, FF_ / 32, L_), wb, 0, stream>>>(w2, w2T, FF_, D_, FF_ * D_);
    k_packbias<<<L_, 256, 0, stream>>>(bq, bk, bv, bqkv);

    // preprocess
    k_pre_init<<<1, 64, 0, stream>>>(maxkey);
    k_rowsum<<<B_, 256, 0, stream>>>(expr, ssum);
    k_compute_e<<<(B_ * G_ + 255) / 256, 256, 0, stream>>>(expr, ssum, ebuf, maxkey);
    k_embed<<<NRP_, 256, 0, stream>>>(ebuf, maxkey, tokemb, cls, x);

    const int NYC = (NYT_ + 7) / 8;              // 67
    int gQKV = 8 * NYC * (QS_ / 128);            // 3216
    int gWO  = 8 * NYC * (D_ / 128);             // 1072
    int gF1  = 8 * NYC * (FF_ / 128);            // 4288
    int gF2  = 8 * NYC * (D_ / 128);             // 1072
    dim3 gBH((NSEQ + 255) / 256, 32);            // (67, 32)
    int gDiag = (NR * 8 + 255) / 256;
    int gLN = NRP_ / 4;                          // 16928 (wave-per-row LN)

    for (int l = 0; l < L_; ++l){
        const float* pjl = projs + (size_t)l * M_ * DH_;
        k_ln<<<gLN, 256, 0, stream>>>(x, hb, ln1g + l * D_, ln1b + l * D_);
        gemm_bf16<3><<<gQKV, 256, 0, stream>>>(hb, wqkvT + (size_t)l * QS_ * D_, bqkv + l * QS_,
                                               nullptr, qkvb, D_, QS_, NYT_);
        k_layer_init<<<64, 256, 0, stream>>>(kfsum, ctx, stab);
        k_diag<<<gDiag, 256, 0, stream>>>(qkvb, diagq, diagk);
        k_kmax<<<gBH, 256, 0, stream>>>(qkvb, pjl, stab);
        k_kv<<<gBH, 256, 0, stream>>>(qkvb, pjl, diagk, stab, kfsum, ctx);
        k_qattn<<<gBH, 256, 0, stream>>>(qkvb, pjl, diagq, kfsum, ctx, hb);   // hb := attn out
        gemm_bf16<1><<<gWO, 256, 0, stream>>>(hb, woT + (size_t)l * D_ * D_, bo + l * D_,
                                              x, nullptr, D_, D_, NYT_);
        k_ln<<<gLN, 256, 0, stream>>>(x, hb, ln2g + l * D_, ln2b + l * D_);
        gemm_bf16<2><<<gF1, 256, 0, stream>>>(hb, w1T + (size_t)l * D_ * FF_, b1 + l * FF_,
                                              nullptr, interb, D_, FF_, NYT_);
        gemm_bf16<1><<<gF2, 256, 0, stream>>>(interb, w2T + (size_t)l * FF_ * D_, b2 + l * D_,
                                              x, nullptr, FF_, D_, NYT_);
    }
    k_final<<<B_, 256, 0, stream>>>(x, pw, pb, out);
}

// Round 16
// 4419.782 us; speedup vs baseline: 1.2012x; 1.0963x over previous
//
#include <hip/hip_runtime.h>
#include <math.h>

#define B_ 4
#define G_ 16906
#define D_ 256
#define H_ 8
#define DH_ 32
#define M_ 110
#define L_ 6
#define FF_ 1024
#define NSEQ (G_ + 1)          // 16907
#define NR (B_ * NSEQ)         // 67628
#define NRP_ 67712             // 529*128, row-padded for 128-tiles
#define NYT_ 529               // row tiles
#define BH_ 32                 // B_*H_
#define QS_ 768                // fused qkv row stride (q:0, k:256, v:512)

static constexpr float SCALE_  = 0.42044820762685725f;   // 32^-0.25
static constexpr float MSCALE_ = 0.09534625892455922f;   // 110^-0.5
static constexpr float FEPS_   = 1e-4f;

// ---- static workspace (module-load-time allocation; R1 proved d_ws too small) ----
#define SZP_ ((size_t)NRP_ * D_)                 // fp32 x buffer
#define WS_FLOATS 92000000                       // ~368 MB
__device__ float g_ws[WS_FLOATS];

typedef __attribute__((ext_vector_type(8))) short bh8;   // 8 bf16 (4 VGPR)
typedef __attribute__((ext_vector_type(4))) float f4;    // MFMA acc

// ---- helpers ----
__device__ __forceinline__ unsigned f2u(float f){
    unsigned u = __float_as_uint(f);
    return (u & 0x80000000u) ? ~u : (u | 0x80000000u);
}
__device__ __forceinline__ float u2f(unsigned u){
    return (u & 0x80000000u) ? __uint_as_float(u & 0x7fffffffu) : __uint_as_float(~u);
}
__device__ __forceinline__ unsigned short f2b(float f){   // fp32 -> bf16 RNE
    unsigned u = __float_as_uint(f);
    return (unsigned short)((u + 0x7fffu + ((u >> 16) & 1u)) >> 16);
}
__device__ __forceinline__ float bf2f(unsigned short u){
    return __uint_as_float(((unsigned)u) << 16);
}

// =============== preprocess ===============
__global__ void k_pre_init(unsigned* __restrict__ maxkey){
    if (threadIdx.x == 0) *maxkey = 0x007fffffu;  // f2u(-inf)
}

__global__ void k_rowsum(const float* __restrict__ expr, float* __restrict__ ssum){
    int b = blockIdx.x, t = threadIdx.x;
    float s = 0.f;
    for (int g = t; g < G_; g += 256) s += fabsf(expr[(size_t)b * G_ + g]);
    __shared__ float red[256];
    red[t] = s; __syncthreads();
    for (int off = 128; off > 0; off >>= 1){ if (t < off) red[t] += red[t + off]; __syncthreads(); }
    if (t == 0) ssum[b] = red[0];
}

__global__ void k_compute_e(const float* __restrict__ expr, const float* __restrict__ ssum,
                            float* __restrict__ ebuf, unsigned* __restrict__ maxkey){
    int t = threadIdx.x;
    int idx = blockIdx.x * 256 + t;
    float e = -INFINITY;
    if (idx < B_ * G_){
        int b = idx / G_;
        float denom = fmaxf(ssum[b], 1e-12f);
        e = log1pf(expr[idx] / denom * 1e4f);
        ebuf[idx] = e;
    }
    __shared__ float red[256];
    red[t] = e; __syncthreads();
    for (int off = 128; off > 0; off >>= 1){ if (t < off) red[t] = fmaxf(red[t], red[t + off]); __syncthreads(); }
    if (t == 0) atomicMax(maxkey, f2u(red[0]));
}

__global__ void k_embed(const float* __restrict__ ebuf, const unsigned* __restrict__ maxkey,
                        const float* __restrict__ tokemb, const float* __restrict__ cls,
                        float* __restrict__ x){
    int row = blockIdx.x, t = threadIdx.x;
    if (row >= NR){ x[(size_t)row * D_ + t] = 0.f; return; }   // pad rows -> 0
    int b = row / NSEQ, i = row % NSEQ;
    float v;
    if (i == 0){
        v = cls[t];
    } else {
        float e = ebuf[(size_t)b * G_ + (i - 1)];
        float mx = u2f(*maxkey);
        float step = mx / 7.0f;                 // linspace(0,mx,8)[:7] = step*j
        int cnt = 0;
        #pragma unroll
        for (int j = 0; j < 7; ++j){
            float bin = step * (float)j;
            cnt += (bin < e) ? 1 : 0;           // searchsorted side='left'
        }
        if (cnt > 6) cnt = 6;
        v = tokemb[cnt * D_ + t];
    }
    x[(size_t)row * D_ + t] = v;
}

// =============== layernorm: fp32 in, bf16 out ===============
// R15: one 64-lane wave per row, shuffle-reduce — no barriers, no LDS.
__launch_bounds__(256)
__global__ void k_ln(const float* __restrict__ X, unsigned short* __restrict__ Y,
                     const float* __restrict__ g, const float* __restrict__ b){
    int wave = threadIdx.x >> 6, lane = threadIdx.x & 63;
    int row = blockIdx.x * 4 + wave;
    float4 v = *(const float4*)&X[(size_t)row * D_ + lane * 4];
    float s = v.x + v.y + v.z + v.w;
    s += __shfl_xor(s, 1);  s += __shfl_xor(s, 2);  s += __shfl_xor(s, 4);
    s += __shfl_xor(s, 8);  s += __shfl_xor(s, 16); s += __shfl_xor(s, 32);
    float mu = s * (1.0f / 256.0f);
    float d0 = v.x - mu, d1 = v.y - mu, d2 = v.z - mu, d3 = v.w - mu;
    float q = d0 * d0 + d1 * d1 + d2 * d2 + d3 * d3;
    q += __shfl_xor(q, 1);  q += __shfl_xor(q, 2);  q += __shfl_xor(q, 4);
    q += __shfl_xor(q, 8);  q += __shfl_xor(q, 16); q += __shfl_xor(q, 32);
    float inv = rsqrtf(q * (1.0f / 256.0f) + 1e-5f);
    float4 gv = *(const float4*)&g[lane * 4];
    float4 bv = *(const float4*)&b[lane * 4];
    ushort4 o;
    o.x = f2b(d0 * inv * gv.x + bv.x);
    o.y = f2b(d1 * inv * gv.y + bv.y);
    o.z = f2b(d2 * inv * gv.z + bv.z);
    o.w = f2b(d3 * inv * gv.w + bv.w);
    *(ushort4*)&Y[(size_t)row * D_ + lane * 4] = o;
}

// =============== weight transpose + bf16 convert: Wout[n][k] = Win[k][n] ===============
__global__ void k_wconv(const float* __restrict__ Win, unsigned short* __restrict__ Wout,
                        int K, int N, int lstride){
    __shared__ float tile[32][33];
    int l = blockIdx.z;
    const float* W = Win + (size_t)l * K * N;
    unsigned short* O = Wout + (size_t)l * lstride;
    int n0 = blockIdx.x * 32, k0 = blockIdx.y * 32;
    int tx = threadIdx.x, ty = threadIdx.y;
    #pragma unroll
    for (int j = 0; j < 4; ++j)
        tile[ty + j * 8][tx] = W[(size_t)(k0 + ty + j * 8) * N + n0 + tx];
    __syncthreads();
    #pragma unroll
    for (int j = 0; j < 4; ++j){
        int n = ty + j * 8;
        O[(size_t)(n0 + n) * K + k0 + tx] = f2b(tile[tx][n]);
    }
}

__global__ void k_packbias(const float* __restrict__ bq, const float* __restrict__ bk,
                           const float* __restrict__ bv, float* __restrict__ o){
    int l = blockIdx.x, t = threadIdx.x;
    o[l * QS_ + t]        = bq[l * D_ + t];
    o[l * QS_ + 256 + t]  = bk[l * D_ + t];
    o[l * QS_ + 512 + t]  = bv[l * D_ + t];
}

// =============== bf16 MFMA GEMM: C = op(A @ Wt^T + bias) ===============
// MODE 0: Cf = A@W + bias (fp32)        MODE 1: Cf += A@W + bias (fp32 residual)
// MODE 2: Cb = bf16(gelu(A@W + bias))   MODE 3: Cb = bf16(A@W + bias)
// R12 XCD swizzle + R11 pipelined K-loop + R8 LDS bf16 epilogue.
#define GP 40
#define EPIT 136
#define BUFSZ (2 * 128 * GP)   // one A+B pair (shorts)
template <int MODE>
__launch_bounds__(256)
__global__ void gemm_bf16(const unsigned short* __restrict__ A,
                          const unsigned short* __restrict__ Wt,
                          const float* __restrict__ bias,
                          float* __restrict__ Cf, unsigned short* __restrict__ Cb,
                          int K, int N, int NY){
    int NX = N >> 7;
    int lid = blockIdx.x;
    int xcd = lid & 7, slot = lid >> 3;
    int colt = slot % NX;
    int rowt = (slot / NX) * 8 + xcd;
    if (rowt >= NY) return;
    int rowBase = rowt * 128, colBase = colt * 128;

    __shared__ __align__(16) unsigned short smem[2 * BUFSZ];
    int tid = threadIdx.x;
    int lane = tid & 63, wave = tid >> 6;
    int wrow = (wave >> 1) * 64, wcol = (wave & 1) * 64;
    int srow = tid >> 2, sslot = tid & 3;
    int m = lane & 15, kg = lane >> 4;
    int sOff = srow * GP + sslot * 8;

    f4 acc[4][4];
    #pragma unroll
    for (int i = 0; i < 4; ++i)
        #pragma unroll
        for (int j = 0; j < 4; ++j) acc[i][j] = (f4){0.f, 0.f, 0.f, 0.f};

    const unsigned short* Ag = A + (size_t)(rowBase + srow) * K + sslot * 8;
    const unsigned short* Bg = Wt + (size_t)(colBase + srow) * K + sslot * 8;

    {
        uint4 a0 = *(const uint4*)(Ag);
        uint4 a1 = *(const uint4*)(Ag + (size_t)64 * K);
        uint4 b0 = *(const uint4*)(Bg);
        uint4 b1 = *(const uint4*)(Bg + (size_t)64 * K);
        *(uint4*)&smem[sOff] = a0;
        *(uint4*)&smem[64 * GP + sOff] = a1;
        *(uint4*)&smem[128 * GP + sOff] = b0;
        *(uint4*)&smem[128 * GP + 64 * GP + sOff] = b1;
    }
    const int NIT = K >> 5;
    for (int it = 0; it < NIT; ++it){
        __syncthreads();
        int cur = (it & 1) * BUFSZ;
        uint4 na0, na1, nb0, nb1;
        bool more = (it + 1 < NIT);
        if (more){
            int k0 = (it + 1) << 5;
            na0 = *(const uint4*)(Ag + k0);
            na1 = *(const uint4*)(Ag + (size_t)64 * K + k0);
            nb0 = *(const uint4*)(Bg + k0);
            nb1 = *(const uint4*)(Bg + (size_t)64 * K + k0);
        }
        bh8 af[4], bf[4];
        #pragma unroll
        for (int mi = 0; mi < 4; ++mi)
            af[mi] = *(const bh8*)&smem[cur + (wrow + mi * 16 + m) * GP + kg * 8];
        #pragma unroll
        for (int ni = 0; ni < 4; ++ni)
            bf[ni] = *(const bh8*)&smem[cur + 128 * GP + (wcol + ni * 16 + m) * GP + kg * 8];
        #pragma unroll
        for (int mi = 0; mi < 4; ++mi)
            #pragma unroll
            for (int ni = 0; ni < 4; ++ni)
                acc[mi][ni] = __builtin_amdgcn_mfma_f32_16x16x32_bf16(af[mi], bf[ni], acc[mi][ni], 0, 0, 0);
        if (more){
            int nxt = ((it + 1) & 1) * BUFSZ;
            *(uint4*)&smem[nxt + sOff] = na0;
            *(uint4*)&smem[nxt + 64 * GP + sOff] = na1;
            *(uint4*)&smem[nxt + 128 * GP + sOff] = nb0;
            *(uint4*)&smem[nxt + 128 * GP + 64 * GP + sOff] = nb1;
        }
    }
    __syncthreads();
    int q4 = lane >> 4;
    if (MODE == 0 || MODE == 1){
        #pragma unroll
        for (int ni = 0; ni < 4; ++ni){
            int col = colBase + wcol + ni * 16 + m;
            float bv = bias[col];
            #pragma unroll
            for (int mi = 0; mi < 4; ++mi){
                int r0 = rowBase + wrow + mi * 16 + q4 * 4;
                #pragma unroll
                for (int rg = 0; rg < 4; ++rg){
                    int row = r0 + rg;
                    float v = acc[mi][ni][rg] + bv;
                    if (MODE == 1) v += Cf[(size_t)row * N + col];
                    Cf[(size_t)row * N + col] = v;
                }
            }
        }
    } else {
        #pragma unroll
        for (int half = 0; half < 2; ++half){
            if ((wrow >> 6) == half){
                #pragma unroll
                for (int ni = 0; ni < 4; ++ni){
                    int coll = wcol + ni * 16 + m;
                    float bv = bias[colBase + coll];
                    #pragma unroll
                    for (int mi = 0; mi < 4; ++mi){
                        int rl0 = (wrow & 63) + mi * 16 + q4 * 4;
                        #pragma unroll
                        for (int rg = 0; rg < 4; ++rg){
                            float v = acc[mi][ni][rg] + bv;
                            if (MODE == 2) v = 0.5f * v * (1.0f + erff(v * 0.70710678118654752f));
                            smem[(rl0 + rg) * EPIT + coll] = f2b(v);
                        }
                    }
                }
            }
            __syncthreads();
            #pragma unroll
            for (int p = 0; p < 4; ++p){
                int idx = p * 256 + tid;
                int r = idx >> 4, ch = idx & 15;
                int grow = rowBase + half * 64 + r;
                uint4 val = *(const uint4*)&smem[r * EPIT + ch * 8];
                *(uint4*)&Cb[(size_t)grow * N + colBase + ch * 8] = val;
            }
            __syncthreads();
        }
    }
}

// =============== attention state init ===============
__global__ void k_layer_init(float* __restrict__ kfsum, float* __restrict__ ctx,
                             unsigned* __restrict__ stab){
    int t = blockIdx.x * 256 + threadIdx.x;
    int nt = gridDim.x * 256;
    if (t == 0) *stab = 0x007fffffu;  // f2u(-inf)
    for (int i = t; i < BH_ * M_; i += nt) kfsum[i] = 0.f;
    for (int i = t; i < BH_ * M_ * DH_; i += nt) ctx[i] = 0.f;
}

// =============== diag from fused qkv buffer ===============
__global__ void k_diag(const unsigned short* __restrict__ qkv,
                       float* __restrict__ diagq, float* __restrict__ diagk){
    int idx = blockIdx.x * 256 + threadIdx.x;   // over NR*8
    if (idx >= NR * 8) return;
    int row = idx >> 3, h = idx & 7;
    const unsigned short* qp = qkv + (size_t)row * QS_ + h * DH_;
    const unsigned short* kp = qkv + (size_t)row * QS_ + 256 + h * DH_;
    float sq = 0.f, sk = 0.f;
    #pragma unroll
    for (int d = 0; d < DH_; ++d){
        float qv = bf2f(qp[d]) * SCALE_; sq += qv * qv;
        float kv = bf2f(kp[d]) * SCALE_; sk += kv * kv;
    }
    diagq[idx] = 0.5f * sq;
    diagk[idx] = 0.5f * sk;
}

// =============== k_kmax: global max of dd (K-side) via MFMA ===============
// R16: uint4 staging (16B/lane; was 2B scalar loads)
__launch_bounds__(256)
__global__ void k_kmax(const unsigned short* __restrict__ qkv, const float* __restrict__ proj,
                       unsigned* __restrict__ stab){
    __shared__ __align__(16) unsigned short pjT[112 * 40];
    __shared__ __align__(16) unsigned short kl[32 * 40];
    __shared__ float red[256];
    int t = threadIdx.x, lane = t & 63, wave = t >> 6;
    int m16 = lane & 15, quad = lane >> 4;
    int bh = blockIdx.y, b = bh >> 3, hh = bh & 7;
    for (int e = t; e < 112 * 32; e += 256){
        int mm = e >> 5, d = e & 31;
        pjT[mm * 40 + d] = f2b((mm < M_) ? SCALE_ * proj[mm * DH_ + d] : 0.f);
    }
    int i0 = blockIdx.x * 256, i1 = min(i0 + 256, NSEQ);
    float mx = -INFINITY;
    int sr = t >> 2, sl = t & 3;          // staging row / 16B chunk
    __syncthreads();
    for (int t0 = i0; t0 < i1; t0 += 32){
        int rows = min(32, i1 - t0);
        if (t < 128){
            uint4 kv = (uint4){0,0,0,0};
            if (sr < rows)
                kv = *(const uint4*)(qkv + ((size_t)(b * NSEQ + t0 + sr)) * QS_ + 256 + hh * DH_ + sl * 8);
            *(uint4*)&kl[sr * 40 + sl * 8] = kv;
        }
        __syncthreads();
        #pragma unroll
        for (int nn = 0; nn < 2; ++nn){
            int nt = wave + nn * 4;
            if (nt >= 7) continue;
            bh8 bfrag = *(const bh8*)&pjT[(nt * 16 + m16) * 40 + quad * 8];
            int f = nt * 16 + m16;
            #pragma unroll
            for (int mt = 0; mt < 2; ++mt){
                bh8 afrag = *(const bh8*)&kl[(mt * 16 + m16) * 40 + quad * 8];
                f4 dd = (f4){0.f,0.f,0.f,0.f};
                dd = __builtin_amdgcn_mfma_f32_16x16x32_bf16(afrag, bfrag, dd, 0, 0, 0);
                #pragma unroll
                for (int rg = 0; rg < 4; ++rg){
                    int r = mt * 16 + quad * 4 + rg;
                    if (f < M_ && r < rows) mx = fmaxf(mx, dd[rg]);
                }
            }
        }
        __syncthreads();
    }
    red[t] = mx; __syncthreads();
    for (int off = 128; off > 0; off >>= 1){ if (t < off) red[t] = fmaxf(red[t], red[t + off]); __syncthreads(); }
    if (t == 0) atomicMax(stab, f2u(red[0]));
}

// =============== k_kv: kf via dd-MFMA, ctx += kf^T @ V via MFMA ===============
// R16: uint4 staging for K and V (V transposed via 8-short LDS scatter)
__launch_bounds__(256)
__global__ void k_kv(const unsigned short* __restrict__ qkv,
                     const float* __restrict__ proj, const float* __restrict__ diagk,
                     const unsigned* __restrict__ stabkey,
                     float* __restrict__ kfsum, float* __restrict__ ctx){
    __shared__ __align__(16) unsigned short pjT[112 * 40];
    __shared__ __align__(16) unsigned short kl[32 * 40];
    __shared__ __align__(16) unsigned short vT[32 * 40];
    __shared__ __align__(16) unsigned short kfT[112 * 40];
    __shared__ float diagl[32];
    int t = threadIdx.x, lane = t & 63, wave = t >> 6;
    int m16 = lane & 15, quad = lane >> 4;
    int bh = blockIdx.y, b = bh >> 3, hh = bh & 7;
    for (int e = t; e < 112 * 32; e += 256){
        int mm = e >> 5, d = e & 31;
        pjT[mm * 40 + d] = f2b((mm < M_) ? SCALE_ * proj[mm * DH_ + d] : 0.f);
    }
    float stab = u2f(*stabkey);
    f4 acc[2][2];
    #pragma unroll
    for (int i = 0; i < 2; ++i)
        #pragma unroll
        for (int j = 0; j < 2; ++j) acc[i][j] = (f4){0.f,0.f,0.f,0.f};
    float ksum = 0.f;
    int i0 = blockIdx.x * 256, i1 = min(i0 + 256, NSEQ);
    int sr = t >> 2, sl = t & 3;
    __syncthreads();
    for (int t0 = i0; t0 < i1; t0 += 32){
        int rows = min(32, i1 - t0);
        if (t < 128){
            size_t base = ((size_t)(b * NSEQ + t0 + sr)) * QS_ + hh * DH_ + sl * 8;
            uint4 kv = (uint4){0,0,0,0}, vv = (uint4){0,0,0,0};
            if (sr < rows){
                kv = *(const uint4*)(qkv + base + 256);
                vv = *(const uint4*)(qkv + base + 512);
            }
            *(uint4*)&kl[sr * 40 + sl * 8] = kv;
            const unsigned short* vs = (const unsigned short*)&vv;
            #pragma unroll
            for (int j = 0; j < 8; ++j)
                vT[(sl * 8 + j) * 40 + sr] = vs[j];
        }
        if (t < 32) diagl[t] = (t < rows) ? diagk[((size_t)(b * NSEQ + t0 + t)) * 8 + hh] : 0.f;
        __syncthreads();
        #pragma unroll
        for (int nn = 0; nn < 2; ++nn){
            int nt = wave + nn * 4;
            if (nt >= 7) continue;
            bh8 bfrag = *(const bh8*)&pjT[(nt * 16 + m16) * 40 + quad * 8];
            int f = nt * 16 + m16;
            #pragma unroll
            for (int mt = 0; mt < 2; ++mt){
                bh8 afrag = *(const bh8*)&kl[(mt * 16 + m16) * 40 + quad * 8];
                f4 dd = (f4){0.f,0.f,0.f,0.f};
                dd = __builtin_amdgcn_mfma_f32_16x16x32_bf16(afrag, bfrag, dd, 0, 0, 0);
                #pragma unroll
                for (int rg = 0; rg < 4; ++rg){
                    int r = mt * 16 + quad * 4 + rg;
                    float kf = 0.f;
                    if (r < rows) kf = MSCALE_ * (__expf(dd[rg] - diagl[r] - stab) + FEPS_);
                    kfT[f * 40 + r] = f2b(kf);
                }
            }
        }
        __syncthreads();
        #pragma unroll
        for (int mm = 0; mm < 2; ++mm){
            int mt = wave + mm * 4;
            if (mt >= 7) continue;
            bh8 afrag = *(const bh8*)&kfT[(mt * 16 + m16) * 40 + quad * 8];
            #pragma unroll
            for (int nt2 = 0; nt2 < 2; ++nt2){
                bh8 bfrag = *(const bh8*)&vT[(nt2 * 16 + m16) * 40 + quad * 8];
                acc[mm][nt2] = __builtin_amdgcn_mfma_f32_16x16x32_bf16(afrag, bfrag, acc[mm][nt2], 0, 0, 0);
            }
        }
        if (t < M_){
            for (int i = 0; i < rows; ++i) ksum += bf2f(kfT[t * 40 + i]);
        }
        __syncthreads();
    }
    float* ctx_bh = ctx + (size_t)bh * M_ * DH_;
    #pragma unroll
    for (int mm = 0; mm < 2; ++mm){
        int mt = wave + mm * 4;
        if (mt >= 7) continue;
        #pragma unroll
        for (int nt2 = 0; nt2 < 2; ++nt2){
            #pragma unroll
            for (int rg = 0; rg < 4; ++rg){
                int f = mt * 16 + quad * 4 + rg;
                int dh = nt2 * 16 + m16;
                if (f < M_) atomicAdd(&ctx_bh[f * DH_ + dh], acc[mm][nt2][rg]);
            }
        }
    }
    if (t < M_) atomicAdd(&kfsum[bh * M_ + t], ksum);
}

// =============== k_qattn: qf via dd-MFMA (rowmax), o = qf @ ctx via MFMA ===============
// R16: uint4 staging for Q
#define CXP 136
__launch_bounds__(256)
__global__ void k_qattn(const unsigned short* __restrict__ qkv, const float* __restrict__ proj,
                        const float* __restrict__ diagq, const float* __restrict__ kfsumg,
                        const float* __restrict__ ctxg, unsigned short* __restrict__ Ob){
    __shared__ __align__(16) unsigned short pjT[112 * 40];
    __shared__ __align__(16) unsigned short ql[32 * 40];
    __shared__ __align__(16) unsigned short qfl[32 * CXP];
    __shared__ __align__(16) unsigned short cxT[32 * CXP];
    __shared__ float kfs[112];
    __shared__ float diagl[32];
    __shared__ float rmax[4][32];
    __shared__ float denl[32];
    int t = threadIdx.x, lane = t & 63, wave = t >> 6;
    int m16 = lane & 15, quad = lane >> 4;
    int bh = blockIdx.y, b = bh >> 3, hh = bh & 7;
    const float* ctx_bh = ctxg + (size_t)bh * M_ * DH_;
    for (int e = t; e < 112 * 32; e += 256){
        int mm = e >> 5, d = e & 31;
        pjT[mm * 40 + d] = f2b((mm < M_) ? SCALE_ * proj[mm * DH_ + d] : 0.f);
    }
    for (int e = t; e < 32 * 128; e += 256){
        int dh = e >> 7, f = e & 127;
        cxT[dh * CXP + f] = f2b((f < M_) ? ctx_bh[f * DH_ + dh] : 0.f);
    }
    for (int e = t; e < 32 * CXP; e += 256) qfl[e] = 0;
    if (t < M_) kfs[t] = kfsumg[bh * M_ + t];
    int i0 = blockIdx.x * 256, i1 = min(i0 + 256, NSEQ);
    int sr = t >> 2, sl = t & 3;
    __syncthreads();
    for (int t0 = i0; t0 < i1; t0 += 32){
        int rows = min(32, i1 - t0);
        if (t < 128){
            uint4 qv = (uint4){0,0,0,0};
            if (sr < rows)
                qv = *(const uint4*)(qkv + ((size_t)(b * NSEQ + t0 + sr)) * QS_ + hh * DH_ + sl * 8);
            *(uint4*)&ql[sr * 40 + sl * 8] = qv;
        }
        if (t < 32) diagl[t] = (t < rows) ? diagq[((size_t)(b * NSEQ + t0 + t)) * 8 + hh] : 0.f;
        __syncthreads();
        f4 ddv[2][2];
        float pm[2][4];
        #pragma unroll
        for (int mt = 0; mt < 2; ++mt)
            #pragma unroll
            for (int rg = 0; rg < 4; ++rg) pm[mt][rg] = -INFINITY;
        #pragma unroll
        for (int nn = 0; nn < 2; ++nn){
            int nt = wave + nn * 4;
            if (nt >= 7) continue;
            bh8 bfrag = *(const bh8*)&pjT[(nt * 16 + m16) * 40 + quad * 8];
            int f = nt * 16 + m16;
            #pragma unroll
            for (int mt = 0; mt < 2; ++mt){
                bh8 afrag = *(const bh8*)&ql[(mt * 16 + m16) * 40 + quad * 8];
                f4 dd = (f4){0.f,0.f,0.f,0.f};
                dd = __builtin_amdgcn_mfma_f32_16x16x32_bf16(afrag, bfrag, dd, 0, 0, 0);
                ddv[nn][mt] = dd;
                if (f < M_){
                    #pragma unroll
                    for (int rg = 0; rg < 4; ++rg) pm[mt][rg] = fmaxf(pm[mt][rg], dd[rg]);
                }
            }
        }
        #pragma unroll
        for (int mt = 0; mt < 2; ++mt)
            #pragma unroll
            for (int rg = 0; rg < 4; ++rg){
                float v = pm[mt][rg];
                v = fmaxf(v, __shfl_xor(v, 1));
                v = fmaxf(v, __shfl_xor(v, 2));
                v = fmaxf(v, __shfl_xor(v, 4));
                v = fmaxf(v, __shfl_xor(v, 8));
                if (m16 == 0) rmax[wave][mt * 16 + quad * 4 + rg] = v;
            }
        __syncthreads();
        #pragma unroll
        for (int nn = 0; nn < 2; ++nn){
            int nt = wave + nn * 4;
            if (nt >= 7) continue;
            int f = nt * 16 + m16;
            #pragma unroll
            for (int mt = 0; mt < 2; ++mt){
                #pragma unroll
                for (int rg = 0; rg < 4; ++rg){
                    int r = mt * 16 + quad * 4 + rg;
                    float mx = fmaxf(fmaxf(rmax[0][r], rmax[1][r]), fmaxf(rmax[2][r], rmax[3][r]));
                    float qf = MSCALE_ * (__expf(ddv[nn][mt][rg] - diagl[r] - mx) + FEPS_);
                    qfl[r * CXP + f] = f2b(qf);
                }
            }
        }
        __syncthreads();
        {
            int r = t >> 3, part = t & 7;
            float s = 0.f;
            for (int f = part; f < M_; f += 8) s += bf2f(qfl[r * CXP + f]) * kfs[f];
            s += __shfl_xor(s, 4); s += __shfl_xor(s, 2); s += __shfl_xor(s, 1);
            if (part == 0) denl[r] = s;
        }
        __syncthreads();
        {
            int mt = wave >> 1, nt = wave & 1;
            f4 oacc = (f4){0.f,0.f,0.f,0.f};
            #pragma unroll
            for (int kk = 0; kk < 4; ++kk){
                bh8 afrag = *(const bh8*)&qfl[(mt * 16 + m16) * CXP + kk * 32 + quad * 8];
                bh8 bfrag = *(const bh8*)&cxT[(nt * 16 + m16) * CXP + kk * 32 + quad * 8];
                oacc = __builtin_amdgcn_mfma_f32_16x16x32_bf16(afrag, bfrag, oacc, 0, 0, 0);
            }
            #pragma unroll
            for (int rg = 0; rg < 4; ++rg){
                int r = mt * 16 + quad * 4 + rg;
                if (r < rows){
                    int grow = b * NSEQ + t0 + r;
                    float o = oacc[rg] / denl[r];
                    Ob[(size_t)grow * D_ + hh * DH_ + nt * 16 + m16] = f2b(o);
                }
            }
        }
        __syncthreads();
    }
}

// =============== final projection: out[b] = x[b,0] @ pw + pb (fp32) ===============
__global__ void k_final(const float* __restrict__ x, const float* __restrict__ pw,
                        const float* __restrict__ pb, float* __restrict__ out){
    int b = blockIdx.x, c = threadIdx.x;
    const float* xr = x + (size_t)b * NSEQ * D_;
    float s = pb[c];
    for (int k = 0; k < D_; ++k) s += xr[k] * pw[k * D_ + c];
    out[b * D_ + c] = s;
}

// =============== host launcher ===============
extern "C" void kernel_launch(void* const* d_in, const int* in_sizes, int n_in,
                              void* d_out, int out_size, void* d_ws, size_t ws_size,
                              hipStream_t stream){
    const float* expr   = (const float*)d_in[0];
    const float* tokemb = (const float*)d_in[1];
    const float* cls    = (const float*)d_in[2];
    const float* ln1g   = (const float*)d_in[3];
    const float* ln1b   = (const float*)d_in[4];
    const float* wq     = (const float*)d_in[5];
    const float* bq     = (const float*)d_in[6];
    const float* wk     = (const float*)d_in[7];
    const float* bk     = (const float*)d_in[8];
    const float* wv     = (const float*)d_in[9];
    const float* bv     = (const float*)d_in[10];
    const float* wo     = (const float*)d_in[11];
    const float* bo     = (const float*)d_in[12];
    const float* ln2g   = (const float*)d_in[13];
    const float* ln2b   = (const float*)d_in[14];
    const float* w1     = (const float*)d_in[15];
    const float* b1     = (const float*)d_in[16];
    const float* w2     = (const float*)d_in[17];
    const float* b2     = (const float*)d_in[18];
    const float* pw     = (const float*)d_in[19];
    const float* pb     = (const float*)d_in[20];
    const float* projs  = (const float*)d_in[21];
    float* out = (float*)d_out;

    float* ws = nullptr;
    if (ws_size >= WS_FLOATS * sizeof(float)) {
        ws = (float*)d_ws;
    } else {
        void* p = nullptr;
        hipGetSymbolAddress(&p, HIP_SYMBOL(g_ws));   // pure query, capture-safe
        ws = (float*)p;
    }

    float* x = ws;                                      // fp32 [NRP][256]
    unsigned short* hb = (unsigned short*)(x + SZP_);   // bf16 [NRP][256]
    unsigned short* qkvb = hb + (size_t)NRP_ * D_;      // bf16 [NRP][768]
    unsigned short* interb = qkvb + (size_t)NRP_ * QS_; // bf16 [NRP][1024]
    unsigned short* wqkvT = interb + (size_t)NRP_ * FF_;    // [6][768][256]
    unsigned short* woT = wqkvT + (size_t)L_ * QS_ * D_;    // [6][256][256]
    unsigned short* w1T = woT + (size_t)L_ * D_ * D_;       // [6][1024][256]
    unsigned short* w2T = w1T + (size_t)L_ * D_ * FF_;      // [6][256][1024]
    float* bqkv  = (float*)(w2T + (size_t)L_ * FF_ * D_);   // [6][768]
    float* diagq = bqkv + L_ * QS_ + 32;
    float* diagk = diagq + (size_t)NR * 8 + 32;
    float* ebuf  = diagk + (size_t)NR * 8 + 32;
    float* ssum  = ebuf + B_ * G_;
    unsigned* maxkey = (unsigned*)(ssum + 8);
    unsigned* stab   = maxkey + 8;
    float* kfsum = (float*)(stab + 8);                 // [BH_][M_]
    float* ctx   = kfsum + BH_ * M_ + 32;              // [BH_][M_][DH_]

    // weights: transpose + bf16 convert (QKV packed into [768][256] per layer)
    dim3 wb(32, 8);
    k_wconv<<<dim3(D_ / 32, D_ / 32, L_), wb, 0, stream>>>(wq, wqkvT,            D_, D_, QS_ * D_);
    k_wconv<<<dim3(D_ / 32, D_ / 32, L_), wb, 0, stream>>>(wk, wqkvT + 256 * D_, D_, D_, QS_ * D_);
    k_wconv<<<dim3(D_ / 32, D_ / 32, L_), wb, 0, stream>>>(wv, wqkvT + 512 * D_, D_, D_, QS_ * D_);
    k_wconv<<<dim3(D_ / 32, D_ / 32, L_), wb, 0, stream>>>(wo, woT, D_, D_, D_ * D_);
    k_wconv<<<dim3(FF_ / 32, D_ / 32, L_), wb, 0, stream>>>(w1, w1T, D_, FF_, D_ * FF_);
    k_wconv<<<dim3(D_ / 32, FF_ / 32, L_), wb, 0, stream>>>(w2, w2T, FF_, D_, FF_ * D_);
    k_packbias<<<L_, 256, 0, stream>>>(bq, bk, bv, bqkv);

    // preprocess
    k_pre_init<<<1, 64, 0, stream>>>(maxkey);
    k_rowsum<<<B_, 256, 0, stream>>>(expr, ssum);
    k_compute_e<<<(B_ * G_ + 255) / 256, 256, 0, stream>>>(expr, ssum, ebuf, maxkey);
    k_embed<<<NRP_, 256, 0, stream>>>(ebuf, maxkey, tokemb, cls, x);

    const int NYC = (NYT_ + 7) / 8;              // 67
    int gQKV = 8 * NYC * (QS_ / 128);            // 3216
    int gWO  = 8 * NYC * (D_ / 128);             // 1072
    int gF1  = 8 * NYC * (FF_ / 128);            // 4288
    int gF2  = 8 * NYC * (D_ / 128);             // 1072
    dim3 gBH((NSEQ + 255) / 256, 32);            // (67, 32)
    int gDiag = (NR * 8 + 255) / 256;
    int gLN = NRP_ / 4;                          // 16928 (wave-per-row LN)

    for (int l = 0; l < L_; ++l){
        const float* pjl = projs + (size_t)l * M_ * DH_;
        k_ln<<<gLN, 256, 0, stream>>>(x, hb, ln1g + l * D_, ln1b + l * D_);
        gemm_bf16<3><<<gQKV, 256, 0, stream>>>(hb, wqkvT + (size_t)l * QS_ * D_, bqkv + l * QS_,
                                               nullptr, qkvb, D_, QS_, NYT_);
        k_layer_init<<<64, 256, 0, stream>>>(kfsum, ctx, stab);
        k_diag<<<gDiag, 256, 0, stream>>>(qkvb, diagq, diagk);
        k_kmax<<<gBH, 256, 0, stream>>>(qkvb, pjl, stab);
        k_kv<<<gBH, 256, 0, stream>>>(qkvb, pjl, diagk, stab, kfsum, ctx);
        k_qattn<<<gBH, 256, 0, stream>>>(qkvb, pjl, diagq, kfsum, ctx, hb);   // hb := attn out
        gemm_bf16<1><<<gWO, 256, 0, stream>>>(hb, woT + (size_t)l * D_ * D_, bo + l * D_,
                                              x, nullptr, D_, D_, NYT_);
        k_ln<<<gLN, 256, 0, stream>>>(x, hb, ln2g + l * D_, ln2b + l * D_);
        gemm_bf16<2><<<gF1, 256, 0, stream>>>(hb, w1T + (size_t)l * D_ * FF_, b1 + l * FF_,
                                              nullptr, interb, D_, FF_, NYT_);
        gemm_bf16<1><<<gF2, 256, 0, stream>>>(interb, w2T + (size_t)l * FF_ * D_, b2 + l * D_,
                                              x, nullptr, FF_, D_, NYT_);
    }
    k_final<<<B_, 256, 0, stream>>>(x, pw, pb, out);
}

// Round 17
// 4356.255 us; speedup vs baseline: 1.2187x; 1.0146x over previous
//
#include <hip/hip_runtime.h>
#include <math.h>

#define B_ 4
#define G_ 16906
#define D_ 256
#define H_ 8
#define DH_ 32
#define M_ 110
#define L_ 6
#define FF_ 1024
#define NSEQ (G_ + 1)          // 16907
#define NR (B_ * NSEQ)         // 67628
#define NRP_ 67712             // 529*128, row-padded for 128-tiles
#define NYT_ 529               // row tiles
#define BH_ 32                 // B_*H_
#define QS_ 768                // fused qkv row stride (q:0, k:256, v:512)

static constexpr float SCALE_  = 0.42044820762685725f;   // 32^-0.25
static constexpr float MSCALE_ = 0.09534625892455922f;   // 110^-0.5
static constexpr float FEPS_   = 1e-4f;

// ---- static workspace (module-load-time allocation; R1 proved d_ws too small) ----
#define SZP_ ((size_t)NRP_ * D_)                 // fp32 x buffer
#define WS_FLOATS 92000000                       // ~368 MB
__device__ float g_ws[WS_FLOATS];

typedef __attribute__((ext_vector_type(8))) short bh8;   // 8 bf16 (4 VGPR)
typedef __attribute__((ext_vector_type(4))) float f4;    // MFMA acc

// ---- helpers ----
__device__ __forceinline__ unsigned f2u(float f){
    unsigned u = __float_as_uint(f);
    return (u & 0x80000000u) ? ~u : (u | 0x80000000u);
}
__device__ __forceinline__ float u2f(unsigned u){
    return (u & 0x80000000u) ? __uint_as_float(u & 0x7fffffffu) : __uint_as_float(~u);
}
__device__ __forceinline__ unsigned short f2b(float f){   // fp32 -> bf16 RNE
    unsigned u = __float_as_uint(f);
    return (unsigned short)((u + 0x7fffu + ((u >> 16) & 1u)) >> 16);
}
__device__ __forceinline__ float bf2f(unsigned short u){
    return __uint_as_float(((unsigned)u) << 16);
}

// =============== preprocess ===============
__global__ void k_pre_init(unsigned* __restrict__ maxkey){
    if (threadIdx.x == 0) *maxkey = 0x007fffffu;  // f2u(-inf)
}

__global__ void k_rowsum(const float* __restrict__ expr, float* __restrict__ ssum){
    int b = blockIdx.x, t = threadIdx.x;
    float s = 0.f;
    for (int g = t; g < G_; g += 256) s += fabsf(expr[(size_t)b * G_ + g]);
    __shared__ float red[256];
    red[t] = s; __syncthreads();
    for (int off = 128; off > 0; off >>= 1){ if (t < off) red[t] += red[t + off]; __syncthreads(); }
    if (t == 0) ssum[b] = red[0];
}

__global__ void k_compute_e(const float* __restrict__ expr, const float* __restrict__ ssum,
                            float* __restrict__ ebuf, unsigned* __restrict__ maxkey){
    int t = threadIdx.x;
    int idx = blockIdx.x * 256 + t;
    float e = -INFINITY;
    if (idx < B_ * G_){
        int b = idx / G_;
        float denom = fmaxf(ssum[b], 1e-12f);
        e = log1pf(expr[idx] / denom * 1e4f);
        ebuf[idx] = e;
    }
    __shared__ float red[256];
    red[t] = e; __syncthreads();
    for (int off = 128; off > 0; off >>= 1){ if (t < off) red[t] = fmaxf(red[t], red[t + off]); __syncthreads(); }
    if (t == 0) atomicMax(maxkey, f2u(red[0]));
}

__global__ void k_embed(const float* __restrict__ ebuf, const unsigned* __restrict__ maxkey,
                        const float* __restrict__ tokemb, const float* __restrict__ cls,
                        float* __restrict__ x){
    int row = blockIdx.x, t = threadIdx.x;
    if (row >= NR){ x[(size_t)row * D_ + t] = 0.f; return; }   // pad rows -> 0
    int b = row / NSEQ, i = row % NSEQ;
    float v;
    if (i == 0){
        v = cls[t];
    } else {
        float e = ebuf[(size_t)b * G_ + (i - 1)];
        float mx = u2f(*maxkey);
        float step = mx / 7.0f;                 // linspace(0,mx,8)[:7] = step*j
        int cnt = 0;
        #pragma unroll
        for (int j = 0; j < 7; ++j){
            float bin = step * (float)j;
            cnt += (bin < e) ? 1 : 0;           // searchsorted side='left'
        }
        if (cnt > 6) cnt = 6;
        v = tokemb[cnt * D_ + t];
    }
    x[(size_t)row * D_ + t] = v;
}

// =============== layernorm: fp32 in, bf16 out ===============
// R15: one 64-lane wave per row, shuffle-reduce — no barriers, no LDS.
__launch_bounds__(256)
__global__ void k_ln(const float* __restrict__ X, unsigned short* __restrict__ Y,
                     const float* __restrict__ g, const float* __restrict__ b){
    int wave = threadIdx.x >> 6, lane = threadIdx.x & 63;
    int row = blockIdx.x * 4 + wave;
    float4 v = *(const float4*)&X[(size_t)row * D_ + lane * 4];
    float s = v.x + v.y + v.z + v.w;
    s += __shfl_xor(s, 1);  s += __shfl_xor(s, 2);  s += __shfl_xor(s, 4);
    s += __shfl_xor(s, 8);  s += __shfl_xor(s, 16); s += __shfl_xor(s, 32);
    float mu = s * (1.0f / 256.0f);
    float d0 = v.x - mu, d1 = v.y - mu, d2 = v.z - mu, d3 = v.w - mu;
    float q = d0 * d0 + d1 * d1 + d2 * d2 + d3 * d3;
    q += __shfl_xor(q, 1);  q += __shfl_xor(q, 2);  q += __shfl_xor(q, 4);
    q += __shfl_xor(q, 8);  q += __shfl_xor(q, 16); q += __shfl_xor(q, 32);
    float inv = rsqrtf(q * (1.0f / 256.0f) + 1e-5f);
    float4 gv = *(const float4*)&g[lane * 4];
    float4 bv = *(const float4*)&b[lane * 4];
    ushort4 o;
    o.x = f2b(d0 * inv * gv.x + bv.x);
    o.y = f2b(d1 * inv * gv.y + bv.y);
    o.z = f2b(d2 * inv * gv.z + bv.z);
    o.w = f2b(d3 * inv * gv.w + bv.w);
    *(ushort4*)&Y[(size_t)row * D_ + lane * 4] = o;
}

// =============== weight transpose + bf16 convert: Wout[n][k] = Win[k][n] ===============
__global__ void k_wconv(const float* __restrict__ Win, unsigned short* __restrict__ Wout,
                        int K, int N, int lstride){
    __shared__ float tile[32][33];
    int l = blockIdx.z;
    const float* W = Win + (size_t)l * K * N;
    unsigned short* O = Wout + (size_t)l * lstride;
    int n0 = blockIdx.x * 32, k0 = blockIdx.y * 32;
    int tx = threadIdx.x, ty = threadIdx.y;
    #pragma unroll
    for (int j = 0; j < 4; ++j)
        tile[ty + j * 8][tx] = W[(size_t)(k0 + ty + j * 8) * N + n0 + tx];
    __syncthreads();
    #pragma unroll
    for (int j = 0; j < 4; ++j){
        int n = ty + j * 8;
        O[(size_t)(n0 + n) * K + k0 + tx] = f2b(tile[tx][n]);
    }
}

__global__ void k_packbias(const float* __restrict__ bq, const float* __restrict__ bk,
                           const float* __restrict__ bv, float* __restrict__ o){
    int l = blockIdx.x, t = threadIdx.x;
    o[l * QS_ + t]        = bq[l * D_ + t];
    o[l * QS_ + 256 + t]  = bk[l * D_ + t];
    o[l * QS_ + 512 + t]  = bv[l * D_ + t];
}

// =============== bf16 MFMA GEMM: C = op(A @ Wt^T + bias) ===============
// MODE 0: Cf = A@W + bias (fp32)        MODE 1: Cf += A@W + bias (fp32 residual)
// MODE 2: Cb = bf16(gelu(A@W + bias))   MODE 3: Cb = bf16(A@W + bias)
// R12 XCD swizzle + R11 pipelined K-loop + R8 LDS bf16 epilogue.
#define GP 40
#define EPIT 136
#define BUFSZ (2 * 128 * GP)   // one A+B pair (shorts)
template <int MODE>
__launch_bounds__(256)
__global__ void gemm_bf16(const unsigned short* __restrict__ A,
                          const unsigned short* __restrict__ Wt,
                          const float* __restrict__ bias,
                          float* __restrict__ Cf, unsigned short* __restrict__ Cb,
                          int K, int N, int NY){
    int NX = N >> 7;
    int lid = blockIdx.x;
    int xcd = lid & 7, slot = lid >> 3;
    int colt = slot % NX;
    int rowt = (slot / NX) * 8 + xcd;
    if (rowt >= NY) return;
    int rowBase = rowt * 128, colBase = colt * 128;

    __shared__ __align__(16) unsigned short smem[2 * BUFSZ];
    int tid = threadIdx.x;
    int lane = tid & 63, wave = tid >> 6;
    int wrow = (wave >> 1) * 64, wcol = (wave & 1) * 64;
    int srow = tid >> 2, sslot = tid & 3;
    int m = lane & 15, kg = lane >> 4;
    int sOff = srow * GP + sslot * 8;

    f4 acc[4][4];
    #pragma unroll
    for (int i = 0; i < 4; ++i)
        #pragma unroll
        for (int j = 0; j < 4; ++j) acc[i][j] = (f4){0.f, 0.f, 0.f, 0.f};

    const unsigned short* Ag = A + (size_t)(rowBase + srow) * K + sslot * 8;
    const unsigned short* Bg = Wt + (size_t)(colBase + srow) * K + sslot * 8;

    {
        uint4 a0 = *(const uint4*)(Ag);
        uint4 a1 = *(const uint4*)(Ag + (size_t)64 * K);
        uint4 b0 = *(const uint4*)(Bg);
        uint4 b1 = *(const uint4*)(Bg + (size_t)64 * K);
        *(uint4*)&smem[sOff] = a0;
        *(uint4*)&smem[64 * GP + sOff] = a1;
        *(uint4*)&smem[128 * GP + sOff] = b0;
        *(uint4*)&smem[128 * GP + 64 * GP + sOff] = b1;
    }
    const int NIT = K >> 5;
    for (int it = 0; it < NIT; ++it){
        __syncthreads();
        int cur = (it & 1) * BUFSZ;
        uint4 na0, na1, nb0, nb1;
        bool more = (it + 1 < NIT);
        if (more){
            int k0 = (it + 1) << 5;
            na0 = *(const uint4*)(Ag + k0);
            na1 = *(const uint4*)(Ag + (size_t)64 * K + k0);
            nb0 = *(const uint4*)(Bg + k0);
            nb1 = *(const uint4*)(Bg + (size_t)64 * K + k0);
        }
        bh8 af[4], bf[4];
        #pragma unroll
        for (int mi = 0; mi < 4; ++mi)
            af[mi] = *(const bh8*)&smem[cur + (wrow + mi * 16 + m) * GP + kg * 8];
        #pragma unroll
        for (int ni = 0; ni < 4; ++ni)
            bf[ni] = *(const bh8*)&smem[cur + 128 * GP + (wcol + ni * 16 + m) * GP + kg * 8];
        #pragma unroll
        for (int mi = 0; mi < 4; ++mi)
            #pragma unroll
            for (int ni = 0; ni < 4; ++ni)
                acc[mi][ni] = __builtin_amdgcn_mfma_f32_16x16x32_bf16(af[mi], bf[ni], acc[mi][ni], 0, 0, 0);
        if (more){
            int nxt = ((it + 1) & 1) * BUFSZ;
            *(uint4*)&smem[nxt + sOff] = na0;
            *(uint4*)&smem[nxt + 64 * GP + sOff] = na1;
            *(uint4*)&smem[nxt + 128 * GP + sOff] = nb0;
            *(uint4*)&smem[nxt + 128 * GP + 64 * GP + sOff] = nb1;
        }
    }
    __syncthreads();
    int q4 = lane >> 4;
    if (MODE == 0 || MODE == 1){
        #pragma unroll
        for (int ni = 0; ni < 4; ++ni){
            int col = colBase + wcol + ni * 16 + m;
            float bv = bias[col];
            #pragma unroll
            for (int mi = 0; mi < 4; ++mi){
                int r0 = rowBase + wrow + mi * 16 + q4 * 4;
                #pragma unroll
                for (int rg = 0; rg < 4; ++rg){
                    int row = r0 + rg;
                    float v = acc[mi][ni][rg] + bv;
                    if (MODE == 1) v += Cf[(size_t)row * N + col];
                    Cf[(size_t)row * N + col] = v;
                }
            }
        }
    } else {
        #pragma unroll
        for (int half = 0; half < 2; ++half){
            if ((wrow >> 6) == half){
                #pragma unroll
                for (int ni = 0; ni < 4; ++ni){
                    int coll = wcol + ni * 16 + m;
                    float bv = bias[colBase + coll];
                    #pragma unroll
                    for (int mi = 0; mi < 4; ++mi){
                        int rl0 = (wrow & 63) + mi * 16 + q4 * 4;
                        #pragma unroll
                        for (int rg = 0; rg < 4; ++rg){
                            float v = acc[mi][ni][rg] + bv;
                            if (MODE == 2) v = 0.5f * v * (1.0f + erff(v * 0.70710678118654752f));
                            smem[(rl0 + rg) * EPIT + coll] = f2b(v);
                        }
                    }
                }
            }
            __syncthreads();
            #pragma unroll
            for (int p = 0; p < 4; ++p){
                int idx = p * 256 + tid;
                int r = idx >> 4, ch = idx & 15;
                int grow = rowBase + half * 64 + r;
                uint4 val = *(const uint4*)&smem[r * EPIT + ch * 8];
                *(uint4*)&Cb[(size_t)grow * N + colBase + ch * 8] = val;
            }
            __syncthreads();
        }
    }
}

// =============== attention state init ===============
__global__ void k_layer_init(float* __restrict__ kfsum, float* __restrict__ ctx,
                             unsigned* __restrict__ stab){
    int t = blockIdx.x * 256 + threadIdx.x;
    int nt = gridDim.x * 256;
    if (t == 0) *stab = 0x007fffffu;  // f2u(-inf)
    for (int i = t; i < BH_ * M_; i += nt) kfsum[i] = 0.f;
    for (int i = t; i < BH_ * M_ * DH_; i += nt) ctx[i] = 0.f;
}

// =============== k_kmax: global max of dd (K-side) via MFMA ===============
// R16: uint4 staging.  R17: computes diagk from the staged K rows (k_diag pass
// eliminated — staging threads already hold the 8 values in registers).
__launch_bounds__(256)
__global__ void k_kmax(const unsigned short* __restrict__ qkv, const float* __restrict__ proj,
                       unsigned* __restrict__ stab, float* __restrict__ diagk){
    __shared__ __align__(16) unsigned short pjT[112 * 40];
    __shared__ __align__(16) unsigned short kl[32 * 40];
    __shared__ float red[256];
    int t = threadIdx.x, lane = t & 63, wave = t >> 6;
    int m16 = lane & 15, quad = lane >> 4;
    int bh = blockIdx.y, b = bh >> 3, hh = bh & 7;
    for (int e = t; e < 112 * 32; e += 256){
        int mm = e >> 5, d = e & 31;
        pjT[mm * 40 + d] = f2b((mm < M_) ? SCALE_ * proj[mm * DH_ + d] : 0.f);
    }
    int i0 = blockIdx.x * 256, i1 = min(i0 + 256, NSEQ);
    float mx = -INFINITY;
    int sr = t >> 2, sl = t & 3;          // staging row / 16B chunk
    __syncthreads();
    for (int t0 = i0; t0 < i1; t0 += 32){
        int rows = min(32, i1 - t0);
        if (t < 128){
            uint4 kv = (uint4){0,0,0,0};
            if (sr < rows)
                kv = *(const uint4*)(qkv + ((size_t)(b * NSEQ + t0 + sr)) * QS_ + 256 + hh * DH_ + sl * 8);
            *(uint4*)&kl[sr * 40 + sl * 8] = kv;
            // R17: diagk from register values (2 shfl + 1 store)
            const unsigned short* ks = (const unsigned short*)&kv;
            float ss = 0.f;
            #pragma unroll
            for (int j = 0; j < 8; ++j){ float xv = bf2f(ks[j]); ss += xv * xv; }
            ss += __shfl_xor(ss, 1); ss += __shfl_xor(ss, 2);
            if (sl == 0 && sr < rows)
                diagk[((size_t)(b * NSEQ + t0 + sr)) * 8 + hh] = 0.5f * SCALE_ * SCALE_ * ss;
        }
        __syncthreads();
        #pragma unroll
        for (int nn = 0; nn < 2; ++nn){
            int nt = wave + nn * 4;
            if (nt >= 7) continue;
            bh8 bfrag = *(const bh8*)&pjT[(nt * 16 + m16) * 40 + quad * 8];
            int f = nt * 16 + m16;
            #pragma unroll
            for (int mt = 0; mt < 2; ++mt){
                bh8 afrag = *(const bh8*)&kl[(mt * 16 + m16) * 40 + quad * 8];
                f4 dd = (f4){0.f,0.f,0.f,0.f};
                dd = __builtin_amdgcn_mfma_f32_16x16x32_bf16(afrag, bfrag, dd, 0, 0, 0);
                #pragma unroll
                for (int rg = 0; rg < 4; ++rg){
                    int r = mt * 16 + quad * 4 + rg;
                    if (f < M_ && r < rows) mx = fmaxf(mx, dd[rg]);
                }
            }
        }
        __syncthreads();
    }
    red[t] = mx; __syncthreads();
    for (int off = 128; off > 0; off >>= 1){ if (t < off) red[t] = fmaxf(red[t], red[t + off]); __syncthreads(); }
    if (t == 0) atomicMax(stab, f2u(red[0]));
}

// =============== k_kv: kf via dd-MFMA, ctx += kf^T @ V via MFMA ===============
// R16: uint4 staging for K and V (V transposed via 8-short LDS scatter)
__launch_bounds__(256)
__global__ void k_kv(const unsigned short* __restrict__ qkv,
                     const float* __restrict__ proj, const float* __restrict__ diagk,
                     const unsigned* __restrict__ stabkey,
                     float* __restrict__ kfsum, float* __restrict__ ctx){
    __shared__ __align__(16) unsigned short pjT[112 * 40];
    __shared__ __align__(16) unsigned short kl[32 * 40];
    __shared__ __align__(16) unsigned short vT[32 * 40];
    __shared__ __align__(16) unsigned short kfT[112 * 40];
    __shared__ float diagl[32];
    int t = threadIdx.x, lane = t & 63, wave = t >> 6;
    int m16 = lane & 15, quad = lane >> 4;
    int bh = blockIdx.y, b = bh >> 3, hh = bh & 7;
    for (int e = t; e < 112 * 32; e += 256){
        int mm = e >> 5, d = e & 31;
        pjT[mm * 40 + d] = f2b((mm < M_) ? SCALE_ * proj[mm * DH_ + d] : 0.f);
    }
    float stab = u2f(*stabkey);
    f4 acc[2][2];
    #pragma unroll
    for (int i = 0; i < 2; ++i)
        #pragma unroll
        for (int j = 0; j < 2; ++j) acc[i][j] = (f4){0.f,0.f,0.f,0.f};
    float ksum = 0.f;
    int i0 = blockIdx.x * 256, i1 = min(i0 + 256, NSEQ);
    int sr = t >> 2, sl = t & 3;
    __syncthreads();
    for (int t0 = i0; t0 < i1; t0 += 32){
        int rows = min(32, i1 - t0);
        if (t < 128){
            size_t base = ((size_t)(b * NSEQ + t0 + sr)) * QS_ + hh * DH_ + sl * 8;
            uint4 kv = (uint4){0,0,0,0}, vv = (uint4){0,0,0,0};
            if (sr < rows){
                kv = *(const uint4*)(qkv + base + 256);
                vv = *(const uint4*)(qkv + base + 512);
            }
            *(uint4*)&kl[sr * 40 + sl * 8] = kv;
            const unsigned short* vs = (const unsigned short*)&vv;
            #pragma unroll
            for (int j = 0; j < 8; ++j)
                vT[(sl * 8 + j) * 40 + sr] = vs[j];
        }
        if (t < 32) diagl[t] = (t < rows) ? diagk[((size_t)(b * NSEQ + t0 + t)) * 8 + hh] : 0.f;
        __syncthreads();
        #pragma unroll
        for (int nn = 0; nn < 2; ++nn){
            int nt = wave + nn * 4;
            if (nt >= 7) continue;
            bh8 bfrag = *(const bh8*)&pjT[(nt * 16 + m16) * 40 + quad * 8];
            int f = nt * 16 + m16;
            #pragma unroll
            for (int mt = 0; mt < 2; ++mt){
                bh8 afrag = *(const bh8*)&kl[(mt * 16 + m16) * 40 + quad * 8];
                f4 dd = (f4){0.f,0.f,0.f,0.f};
                dd = __builtin_amdgcn_mfma_f32_16x16x32_bf16(afrag, bfrag, dd, 0, 0, 0);
                #pragma unroll
                for (int rg = 0; rg < 4; ++rg){
                    int r = mt * 16 + quad * 4 + rg;
                    float kf = 0.f;
                    if (r < rows) kf = MSCALE_ * (__expf(dd[rg] - diagl[r] - stab) + FEPS_);
                    kfT[f * 40 + r] = f2b(kf);
                }
            }
        }
        __syncthreads();
        #pragma unroll
        for (int mm = 0; mm < 2; ++mm){
            int mt = wave + mm * 4;
            if (mt >= 7) continue;
            bh8 afrag = *(const bh8*)&kfT[(mt * 16 + m16) * 40 + quad * 8];
            #pragma unroll
            for (int nt2 = 0; nt2 < 2; ++nt2){
                bh8 bfrag = *(const bh8*)&vT[(nt2 * 16 + m16) * 40 + quad * 8];
                acc[mm][nt2] = __builtin_amdgcn_mfma_f32_16x16x32_bf16(afrag, bfrag, acc[mm][nt2], 0, 0, 0);
            }
        }
        if (t < M_){
            for (int i = 0; i < rows; ++i) ksum += bf2f(kfT[t * 40 + i]);
        }
        __syncthreads();
    }
    float* ctx_bh = ctx + (size_t)bh * M_ * DH_;
    #pragma unroll
    for (int mm = 0; mm < 2; ++mm){
        int mt = wave + mm * 4;
        if (mt >= 7) continue;
        #pragma unroll
        for (int nt2 = 0; nt2 < 2; ++nt2){
            #pragma unroll
            for (int rg = 0; rg < 4; ++rg){
                int f = mt * 16 + quad * 4 + rg;
                int dh = nt2 * 16 + m16;
                if (f < M_) atomicAdd(&ctx_bh[f * DH_ + dh], acc[mm][nt2][rg]);
            }
        }
    }
    if (t < M_) atomicAdd(&kfsum[bh * M_ + t], ksum);
}

// =============== k_qattn: qf via dd-MFMA (rowmax), o = qf @ ctx via MFMA ===============
// R16: uint4 staging for Q.  R17: diagq computed inline from the staged ql tile
// (8 threads/row + shfl; ordered by the existing rmax barrier).
#define CXP 136
__launch_bounds__(256)
__global__ void k_qattn(const unsigned short* __restrict__ qkv, const float* __restrict__ proj,
                        const float* __restrict__ kfsumg,
                        const float* __restrict__ ctxg, unsigned short* __restrict__ Ob){
    __shared__ __align__(16) unsigned short pjT[112 * 40];
    __shared__ __align__(16) unsigned short ql[32 * 40];
    __shared__ __align__(16) unsigned short qfl[32 * CXP];
    __shared__ __align__(16) unsigned short cxT[32 * CXP];
    __shared__ float kfs[112];
    __shared__ float diagl[32];
    __shared__ float rmax[4][32];
    __shared__ float denl[32];
    int t = threadIdx.x, lane = t & 63, wave = t >> 6;
    int m16 = lane & 15, quad = lane >> 4;
    int bh = blockIdx.y, b = bh >> 3, hh = bh & 7;
    const float* ctx_bh = ctxg + (size_t)bh * M_ * DH_;
    for (int e = t; e < 112 * 32; e += 256){
        int mm = e >> 5, d = e & 31;
        pjT[mm * 40 + d] = f2b((mm < M_) ? SCALE_ * proj[mm * DH_ + d] : 0.f);
    }
    for (int e = t; e < 32 * 128; e += 256){
        int dh = e >> 7, f = e & 127;
        cxT[dh * CXP + f] = f2b((f < M_) ? ctx_bh[f * DH_ + dh] : 0.f);
    }
    for (int e = t; e < 32 * CXP; e += 256) qfl[e] = 0;
    if (t < M_) kfs[t] = kfsumg[bh * M_ + t];
    int i0 = blockIdx.x * 256, i1 = min(i0 + 256, NSEQ);
    int sr = t >> 2, sl = t & 3;
    __syncthreads();
    for (int t0 = i0; t0 < i1; t0 += 32){
        int rows = min(32, i1 - t0);
        if (t < 128){
            uint4 qv = (uint4){0,0,0,0};
            if (sr < rows)
                qv = *(const uint4*)(qkv + ((size_t)(b * NSEQ + t0 + sr)) * QS_ + hh * DH_ + sl * 8);
            *(uint4*)&ql[sr * 40 + sl * 8] = qv;
        }
        __syncthreads();
        // R17: inline diagq from staged ql (visible after the rmax barrier below)
        {
            int r = t >> 3, part = t & 7;
            float s = 0.f;
            #pragma unroll
            for (int d0 = 0; d0 < 4; ++d0){
                float qv2 = bf2f(ql[r * 40 + part * 4 + d0]);
                s += qv2 * qv2;
            }
            s += __shfl_xor(s, 1); s += __shfl_xor(s, 2); s += __shfl_xor(s, 4);
            if (part == 0) diagl[r] = 0.5f * SCALE_ * SCALE_ * s;
        }
        f4 ddv[2][2];
        float pm[2][4];
        #pragma unroll
        for (int mt = 0; mt < 2; ++mt)
            #pragma unroll
            for (int rg = 0; rg < 4; ++rg) pm[mt][rg] = -INFINITY;
        #pragma unroll
        for (int nn = 0; nn < 2; ++nn){
            int nt = wave + nn * 4;
            if (nt >= 7) continue;
            bh8 bfrag = *(const bh8*)&pjT[(nt * 16 + m16) * 40 + quad * 8];
            int f = nt * 16 + m16;
            #pragma unroll
            for (int mt = 0; mt < 2; ++mt){
                bh8 afrag = *(const bh8*)&ql[(mt * 16 + m16) * 40 + quad * 8];
                f4 dd = (f4){0.f,0.f,0.f,0.f};
                dd = __builtin_amdgcn_mfma_f32_16x16x32_bf16(afrag, bfrag, dd, 0, 0, 0);
                ddv[nn][mt] = dd;
                if (f < M_){
                    #pragma unroll
                    for (int rg = 0; rg < 4; ++rg) pm[mt][rg] = fmaxf(pm[mt][rg], dd[rg]);
                }
            }
        }
        #pragma unroll
        for (int mt = 0; mt < 2; ++mt)
            #pragma unroll
            for (int rg = 0; rg < 4; ++rg){
                float v = pm[mt][rg];
                v = fmaxf(v, __shfl_xor(v, 1));
                v = fmaxf(v, __shfl_xor(v, 2));
                v = fmaxf(v, __shfl_xor(v, 4));
                v = fmaxf(v, __shfl_xor(v, 8));
                if (m16 == 0) rmax[wave][mt * 16 + quad * 4 + rg] = v;
            }
        __syncthreads();
        #pragma unroll
        for (int nn = 0; nn < 2; ++nn){
            int nt = wave + nn * 4;
            if (nt >= 7) continue;
            int f = nt * 16 + m16;
            #pragma unroll
            for (int mt = 0; mt < 2; ++mt){
                #pragma unroll
                for (int rg = 0; rg < 4; ++rg){
                    int r = mt * 16 + quad * 4 + rg;
                    float mx = fmaxf(fmaxf(rmax[0][r], rmax[1][r]), fmaxf(rmax[2][r], rmax[3][r]));
                    float qf = MSCALE_ * (__expf(ddv[nn][mt][rg] - diagl[r] - mx) + FEPS_);
                    qfl[r * CXP + f] = f2b(qf);
                }
            }
        }
        __syncthreads();
        {
            int r = t >> 3, part = t & 7;
            float s = 0.f;
            for (int f = part; f < M_; f += 8) s += bf2f(qfl[r * CXP + f]) * kfs[f];
            s += __shfl_xor(s, 4); s += __shfl_xor(s, 2); s += __shfl_xor(s, 1);
            if (part == 0) denl[r] = s;
        }
        __syncthreads();
        {
            int mt = wave >> 1, nt = wave & 1;
            f4 oacc = (f4){0.f,0.f,0.f,0.f};
            #pragma unroll
            for (int kk = 0; kk < 4; ++kk){
                bh8 afrag = *(const bh8*)&qfl[(mt * 16 + m16) * CXP + kk * 32 + quad * 8];
                bh8 bfrag = *(const bh8*)&cxT[(nt * 16 + m16) * CXP + kk * 32 + quad * 8];
                oacc = __builtin_amdgcn_mfma_f32_16x16x32_bf16(afrag, bfrag, oacc, 0, 0, 0);
            }
            #pragma unroll
            for (int rg = 0; rg < 4; ++rg){
                int r = mt * 16 + quad * 4 + rg;
                if (r < rows){
                    int grow = b * NSEQ + t0 + r;
                    float o = oacc[rg] / denl[r];
                    Ob[(size_t)grow * D_ + hh * DH_ + nt * 16 + m16] = f2b(o);
                }
            }
        }
        __syncthreads();
    }
}

// =============== final projection: out[b] = x[b,0] @ pw + pb (fp32) ===============
__global__ void k_final(const float* __restrict__ x, const float* __restrict__ pw,
                        const float* __restrict__ pb, float* __restrict__ out){
    int b = blockIdx.x, c = threadIdx.x;
    const float* xr = x + (size_t)b * NSEQ * D_;
    float s = pb[c];
    for (int k = 0; k < D_; ++k) s += xr[k] * pw[k * D_ + c];
    out[b * D_ + c] = s;
}

// =============== host launcher ===============
extern "C" void kernel_launch(void* const* d_in, const int* in_sizes, int n_in,
                              void* d_out, int out_size, void* d_ws, size_t ws_size,
                              hipStream_t stream){
    const float* expr   = (const float*)d_in[0];
    const float* tokemb = (const float*)d_in[1];
    const float* cls    = (const float*)d_in[2];
    const float* ln1g   = (const float*)d_in[3];
    const float* ln1b   = (const float*)d_in[4];
    const float* wq     = (const float*)d_in[5];
    const float* bq     = (const float*)d_in[6];
    const float* wk     = (const float*)d_in[7];
    const float* bk     = (const float*)d_in[8];
    const float* wv     = (const float*)d_in[9];
    const float* bv     = (const float*)d_in[10];
    const float* wo     = (const float*)d_in[11];
    const float* bo     = (const float*)d_in[12];
    const float* ln2g   = (const float*)d_in[13];
    const float* ln2b   = (const float*)d_in[14];
    const float* w1     = (const float*)d_in[15];
    const float* b1     = (const float*)d_in[16];
    const float* w2     = (const float*)d_in[17];
    const float* b2     = (const float*)d_in[18];
    const float* pw     = (const float*)d_in[19];
    const float* pb     = (const float*)d_in[20];
    const float* projs  = (const float*)d_in[21];
    float* out = (float*)d_out;

    float* ws = nullptr;
    if (ws_size >= WS_FLOATS * sizeof(float)) {
        ws = (float*)d_ws;
    } else {
        void* p = nullptr;
        hipGetSymbolAddress(&p, HIP_SYMBOL(g_ws));   // pure query, capture-safe
        ws = (float*)p;
    }

    float* x = ws;                                      // fp32 [NRP][256]
    unsigned short* hb = (unsigned short*)(x + SZP_);   // bf16 [NRP][256]
    unsigned short* qkvb = hb + (size_t)NRP_ * D_;      // bf16 [NRP][768]
    unsigned short* interb = qkvb + (size_t)NRP_ * QS_; // bf16 [NRP][1024]
    unsigned short* wqkvT = interb + (size_t)NRP_ * FF_;    // [6][768][256]
    unsigned short* woT = wqkvT + (size_t)L_ * QS_ * D_;    // [6][256][256]
    unsigned short* w1T = woT + (size_t)L_ * D_ * D_;       // [6][1024][256]
    unsigned short* w2T = w1T + (size_t)L_ * D_ * FF_;      // [6][256][1024]
    float* bqkv  = (float*)(w2T + (size_t)L_ * FF_ * D_);   // [6][768]
    float* diagk = bqkv + L_ * QS_ + 32;                    // [NR*8]
    float* ebuf  = diagk + (size_t)NR * 8 + 32;
    float* ssum  = ebuf + B_ * G_;
    unsigned* maxkey = (unsigned*)(ssum + 8);
    unsigned* stab   = maxkey + 8;
    float* kfsum = (float*)(stab + 8);                 // [BH_][M_]
    float* ctx   = kfsum + BH_ * M_ + 32;              // [BH_][M_][DH_]

    // weights: transpose + bf16 convert (QKV packed into [768][256] per layer)
    dim3 wb(32, 8);
    k_wconv<<<dim3(D_ / 32, D_ / 32, L_), wb, 0, stream>>>(wq, wqkvT,            D_, D_, QS_ * D_);
    k_wconv<<<dim3(D_ / 32, D_ / 32, L_), wb, 0, stream>>>(wk, wqkvT + 256 * D_, D_, D_, QS_ * D_);
    k_wconv<<<dim3(D_ / 32, D_ / 32, L_), wb, 0, stream>>>(wv, wqkvT + 512 * D_, D_, D_, QS_ * D_);
    k_wconv<<<dim3(D_ / 32, D_ / 32, L_), wb, 0, stream>>>(wo, woT, D_, D_, D_ * D_);
    k_wconv<<<dim3(FF_ / 32, D_ / 32, L_), wb, 0, stream>>>(w1, w1T, D_, FF_, D_ * FF_);
    k_wconv<<<dim3(D_ / 32, FF_ / 32, L_), wb, 0, stream>>>(w2, w2T, FF_, D_, FF_ * D_);
    k_packbias<<<L_, 256, 0, stream>>>(bq, bk, bv, bqkv);

    // preprocess
    k_pre_init<<<1, 64, 0, stream>>>(maxkey);
    k_rowsum<<<B_, 256, 0, stream>>>(expr, ssum);
    k_compute_e<<<(B_ * G_ + 255) / 256, 256, 0, stream>>>(expr, ssum, ebuf, maxkey);
    k_embed<<<NRP_, 256, 0, stream>>>(ebuf, maxkey, tokemb, cls, x);

    const int NYC = (NYT_ + 7) / 8;              // 67
    int gQKV = 8 * NYC * (QS_ / 128);            // 3216
    int gWO  = 8 * NYC * (D_ / 128);             // 1072
    int gF1  = 8 * NYC * (FF_ / 128);            // 4288
    int gF2  = 8 * NYC * (D_ / 128);             // 1072
    dim3 gBH((NSEQ + 255) / 256, 32);            // (67, 32)
    int gLN = NRP_ / 4;                          // 16928 (wave-per-row LN)

    for (int l = 0; l < L_; ++l){
        const float* pjl = projs + (size_t)l * M_ * DH_;
        k_ln<<<gLN, 256, 0, stream>>>(x, hb, ln1g + l * D_, ln1b + l * D_);
        gemm_bf16<3><<<gQKV, 256, 0, stream>>>(hb, wqkvT + (size_t)l * QS_ * D_, bqkv + l * QS_,
                                               nullptr, qkvb, D_, QS_, NYT_);
        k_layer_init<<<64, 256, 0, stream>>>(kfsum, ctx, stab);
        k_kmax<<<gBH, 256, 0, stream>>>(qkvb, pjl, stab, diagk);
        k_kv<<<gBH, 256, 0, stream>>>(qkvb, pjl, diagk, stab, kfsum, ctx);
        k_qattn<<<gBH, 256, 0, stream>>>(qkvb, pjl, kfsum, ctx, hb);   // hb := attn out
        gemm_bf16<1><<<gWO, 256, 0, stream>>>(hb, woT + (size_t)l * D_ * D_, bo + l * D_,
                                              x, nullptr, D_, D_, NYT_);
        k_ln<<<gLN, 256, 0, stream>>>(x, hb, ln2g + l * D_, ln2b + l * D_);
        gemm_bf16<2><<<gF1, 256, 0, stream>>>(hb, w1T + (size_t)l * D_ * FF_, b1 + l * FF_,
                                              nullptr, interb, D_, FF_, NYT_);
        gemm_bf16<1><<<gF2, 256, 0, stream>>>(interb, w2T + (size_t)l * FF_ * D_, b2 + l * D_,
                                              x, nullptr, FF_, D_, NYT_);
    }
    k_final<<<B_, 256, 0, stream>>>(x, pw, pb, out);
}